// Round 6
// baseline (383.895 us; speedup 1.0000x reference)
//
#include <hip/hip_runtime.h>
#include <hip/hip_bf16.h>
#include <math.h>

#define BATCH 1024
#define LABEL 128
#define LATENT 512
#define NTOT 1152  // 1024 + 128

typedef short short8 __attribute__((ext_vector_type(8)));
typedef float f32x16 __attribute__((ext_vector_type(16)));

__device__ __forceinline__ unsigned short f2bf(float f) {
    __hip_bfloat16 h = __float2bfloat16(f);
    return *(unsigned short*)&h;
}
__device__ __forceinline__ float bf2f(unsigned short u) {
    __hip_bfloat16 h; *(unsigned short*)&h = u;
    return __bfloat162float(h);
}

#define BSTR ((size_t)512 * 3136)
#define ASTR ((size_t)NTOT * 3136)
#define A2STR ((size_t)BATCH * 512)
#define W2STR ((size_t)LABEL * 512)

// conv1 output layout (per image): 2 bf16 planes of 6400 ushorts.
// Plane = 196 compact pixels (14x14) x 32ch, granule = 64B, slot-swizzled:
// off = p*32 + (((oc>>3) ^ (p>>1)) & 3)*8 + (oc&7).  Granules 196..199 zeroed.
//
// NUMERICS RULE (r15): w_kernel/rho keep r14-exact op order (Hopfield sign
// cascades). COVERAGE RULE (r16): conv1 writes all 196 pixels (xh loop).
// r19 lesson: do not add kernels to the tail (launch+roundtrip > savings).
// r22/r23: conv2 v9.1 = 2 img/block dual-ocT waves, 83.3us PROVEN OPTIMUM.
// r24 (1 img, more occ) = 91.5; r25 (manual B-pipeline) = 90.2 — both WORSE.
// r26: rho fused into t_kernel; w_kernel LDS-tiled. 376.8us.
// r27: conv1 FUSED into conv2 (conv12_mfma): conv1 computes directly into the
// pl[] LDS tile (r17 code verbatim, ob -> LDS). Removes conv1_pool launch,
// 29.5MB scattered HBM writes + 15.3MB reads + staging loop. LDS 58.5KB,
// same 2 blocks/CU. conv1 regs die before acc goes live. Bit-exact.

// ------- merged prep (r17 proven) ---------------------------------------------
__global__ __launch_bounds__(256) void prep(const float* __restrict__ c2w,
                                            const float* __restrict__ f1w,
                                            const float* __restrict__ fnw,
                                            unsigned short* __restrict__ Bf,
                                            unsigned short* __restrict__ Bw2,
                                            unsigned short* __restrict__ Bn2) {
    int idx = blockIdx.x * 256 + threadIdx.x;
    if (idx < 102400) {
        int j = idx & 7, lane = (idx >> 3) & 63, ocT = (idx >> 9) & 1, s = idx >> 10;
        int q = lane >> 5, nn = lane & 31;
        int k = 16 * s + 8 * q + j;
        int tap = k >> 5, ic = k & 31;
        int oc = 32 * ocT + nn;
        float v = c2w[oc * 800 + ic * 25 + tap];
        unsigned short b1 = f2bf(v);
        unsigned short b2 = f2bf(v - bf2f(b1));
        size_t base = ((size_t)(s * 2 + ocT) * 2) * 512 + lane * 8 + j;
        Bf[base] = b1; Bf[base + 512] = b2;
        return;
    }
    int i2 = idx - 102400;
    if (i2 < 512 * 3136) {
        float v = f1w[i2];
        unsigned short b1 = f2bf(v);
        unsigned short b2 = f2bf(v - bf2f(b1));
        Bw2[i2] = b1; Bw2[BSTR + i2] = b2;
        return;
    }
    int i3 = i2 - 512 * 3136;
    if (i3 >= 128 * 512) return;
    float v = fnw[i3];
    unsigned short b1 = f2bf(v);
    unsigned short b2 = f2bf(v - bf2f(b1));
    Bn2[i3] = b1; Bn2[W2STR + i3] = b2;
}

// ------- conv2 kloop/epi (r23 proven, verbatim) -------------------------------
template<int NT>
__device__ __forceinline__ void conv2_kloop2(const unsigned short* __restrict__ pl,
                                             const unsigned short* __restrict__ Bf,
                                             const int lane, const int q,
                                             const int* __restrict__ ym,
                                             const int* __restrict__ xm,
                                             const int* __restrict__ mm,
                                             const float bs0, const float bs1,
                                             f32x16* __restrict__ acc) {
    #pragma unroll
    for (int im = 0; im < 2; ++im)
    #pragma unroll
    for (int oc = 0; oc < 2; ++oc) {
        const float bs = oc ? bs1 : bs0;
        #pragma unroll
        for (int tt = 0; tt < NT; ++tt)
        #pragma unroll
        for (int r = 0; r < 16; ++r) acc[(im * 2 + oc) * NT + tt][r] = bs;
    }
    for (int s = 0; s < 50; ++s) {
        const unsigned short* bp = Bf + (size_t)s * 2048 + lane * 8;
        short8 b1[2], b2[2];
        b1[0] = *(const short8*)(bp);
        b2[0] = *(const short8*)(bp + 512);
        b1[1] = *(const short8*)(bp + 1024);
        b2[1] = *(const short8*)(bp + 1536);
        const int kb = 16 * s + 8 * q;
        const int tap = kb >> 5, g = (kb & 31) >> 3;
        const int ky = (tap * 13) >> 6;       // exact /5 for tap<25
        const int kx = tap - ky * 5;
        const int iyk = ky - 2, ixk = kx - 2;
        const int pq2 = iyk * 14 + ixk;
        int addr[NT];
        #pragma unroll
        for (int tt = 0; tt < NT; ++tt) {
            int iy = ym[tt] + iyk, ix = xm[tt] + ixk;
            int valid = ((unsigned)iy < 14u) & ((unsigned)ix < 14u);
            int cpt = valid ? (mm[tt] + pq2) : 196;
            addr[tt] = cpt * 32 + (((g ^ (cpt >> 1)) & 3) << 3);
        }
        short8 a1[2][NT], a2[2][NT];
        #pragma unroll
        for (int im = 0; im < 2; ++im) {
            const unsigned short* pli = pl + im * 12800;
            #pragma unroll
            for (int tt = 0; tt < NT; ++tt) {
                a1[im][tt] = *(const short8*)(pli + addr[tt]);
                a2[im][tt] = *(const short8*)(pli + 6400 + addr[tt]);
            }
        }
        #pragma unroll
        for (int im = 0; im < 2; ++im)
        #pragma unroll
        for (int oc = 0; oc < 2; ++oc)
        #pragma unroll
        for (int tt = 0; tt < NT; ++tt) {
            f32x16 a = acc[(im * 2 + oc) * NT + tt];
            a = __builtin_amdgcn_mfma_f32_32x32x16_bf16(a1[im][tt], b1[oc], a, 0, 0, 0);
            a = __builtin_amdgcn_mfma_f32_32x32x16_bf16(a1[im][tt], b2[oc], a, 0, 0, 0);
            a = __builtin_amdgcn_mfma_f32_32x32x16_bf16(a2[im][tt], b1[oc], a, 0, 0, 0);
            acc[(im * 2 + oc) * NT + tt] = a;
        }
    }
}

template<int NT>
__device__ __forceinline__ void conv2_epi(const f32x16* __restrict__ acc,
                                          float* __restrict__ hx,
                                          const int wv, const int m_, const int q) {
    #pragma unroll
    for (int im = 0; im < 2; ++im) {
        float* hxi = hx + im * 6400;
        #pragma unroll
        for (int oc = 0; oc < 2; ++oc) {
            const int occ = 32 * oc + m_;
            #pragma unroll
            for (int tt = 0; tt < NT; ++tt)
            #pragma unroll
            for (int e = 0; e < 8; ++e) {
                const int reg = 2 * e;
                const int r = (reg & 3) + 8 * (reg >> 2) + 4 * q;
                const int m = 32 * (2 * wv + tt) + r;
                if (m < 196) {
                    float xm2 = fmaxf(acc[(im * 2 + oc) * NT + tt][reg],
                                      acc[(im * 2 + oc) * NT + tt][reg + 1]);
                    int y = (m * 2341) >> 15;
                    int px = (m - 14 * y) >> 1;
                    hxi[(y * 7 + px) * 65 + occ] = xm2;
                }
            }
        }
    }
}

// ------- conv12_mfma (r27): conv1 fused, output direct to LDS -----------------
__global__ __launch_bounds__(256, 2) void conv12_mfma(const float* __restrict__ image,
                                                      const float* __restrict__ limg,
                                                      const float* __restrict__ c1w,
                                                      const float* __restrict__ c1b,
                                                      const unsigned short* __restrict__ Bf,
                                                      const float* __restrict__ bias,
                                                      unsigned short* __restrict__ out2) {
    const int n2 = blockIdx.x;            // image pair (2*n2, 2*n2+1)
    __shared__ __align__(16) unsigned short pl[2 * 12800];
    __shared__ float pin[32][32];
    __shared__ float wts[800];
    const int tid = threadIdx.x;
    const int lane = tid & 63, wv = tid >> 6;

    // zero dead granules (196..199) of all 4 planes + zero pin + load conv1 wts
    for (int i = tid; i < 512; i += 256) {
        int imz = i >> 8, rr = i & 255;
        int pl_ = rr >> 7, r = rr & 127;
        pl[imz * 12800 + pl_ * 6400 + 6272 + r] = 0;
    }
    for (int idx = tid; idx < 1024; idx += 256) ((float*)pin)[idx] = 0.f;
    for (int idx = tid; idx < 800; idx += 256) wts[idx] = c1w[idx];
    __syncthreads();

    // ---- conv1 phase (r17 code verbatim, ob -> LDS), 2 images sequential ----
    {
        const int oc = tid & 31;
        float wk[25];
        #pragma unroll
        for (int k = 0; k < 25; ++k) wk[k] = wts[oc * 25 + k];
        const float b = c1b[oc];
        const int slot_lo = (oc & 7);
        const int gq = oc >> 3;
        for (int im = 0; im < 2; ++im) {
            const int n = 2 * n2 + im;
            const float* in = (n < BATCH) ? (image + (size_t)n * 784)
                                          : (limg + (size_t)(n - BATCH) * 784);
            for (int idx = tid; idx < 784; idx += 256) {
                int y = idx / 28, x = idx % 28;
                pin[y + 2][x + 2] = in[idx];
            }
            __syncthreads();
            unsigned short* ob = pl + im * 12800;
            for (int it = 0; it < 2; ++it) {
                const int py = (tid >> 5) + it * 8;
                if (py >= 14) continue;
                #pragma unroll
                for (int xh = 0; xh < 2; ++xh) {
                    const int acol = xh ? 12 : 0;
                    const int off = xh ? 2 : 0;
                    float a0[14], a1[14];
                    #pragma unroll
                    for (int c = 0; c < 14; ++c) { a0[c] = b; a1[c] = b; }
                    #pragma unroll
                    for (int t = 0; t < 6; ++t) {
                        float row[20];
                        const float4* rp = (const float4*)&pin[2 * py + t][acol];
                        #pragma unroll
                        for (int v = 0; v < 5; ++v) {
                            float4 f = rp[v];
                            row[4 * v] = f.x; row[4 * v + 1] = f.y;
                            row[4 * v + 2] = f.z; row[4 * v + 3] = f.w;
                        }
                        if (t < 5) {
                            #pragma unroll
                            for (int kx = 0; kx < 5; ++kx) {
                                float w0 = wk[t * 5 + kx];
                                #pragma unroll
                                for (int c = 0; c < 14; ++c)
                                    a0[c] = fmaf(row[c + kx + off], w0, a0[c]);
                            }
                        }
                        if (t >= 1) {
                            #pragma unroll
                            for (int kx = 0; kx < 5; ++kx) {
                                float w1 = wk[(t - 1) * 5 + kx];
                                #pragma unroll
                                for (int c = 0; c < 14; ++c)
                                    a1[c] = fmaf(row[c + kx + off], w1, a1[c]);
                            }
                        }
                    }
                    #pragma unroll
                    for (int px = 0; px < 7; ++px) {
                        float v = fmaxf(fmaxf(a0[2 * px], a0[2 * px + 1]),
                                        fmaxf(a1[2 * px], a1[2 * px + 1]));
                        v = fmaxf(v, 0.f);
                        unsigned short b1 = f2bf(v);
                        unsigned short b2 = f2bf(v - bf2f(b1));
                        int p = py * 14 + 7 * xh + px;
                        int offo = p * 32 + (((gq ^ (p >> 1)) & 3) << 3) + slot_lo;
                        ob[offo] = b1; ob[6400 + offo] = b2;
                    }
                }
            }
            __syncthreads();   // pl[im] complete; pin free for next image
        }
    }

    // ---- conv2 phase (r23 verbatim) ----
    const int m_ = lane & 31, q = lane >> 5;
    int ym[2], xm[2], mm[2];
    #pragma unroll
    for (int tt = 0; tt < 2; ++tt) {
        int t = 2 * wv + tt;
        if (t > 6) t = 6;               // wv=3,tt=1 dummy (kloop<1> never uses it)
        int m = 32 * t + m_;
        mm[tt] = m;
        ym[tt] = m / 14;
        xm[tt] = m - 14 * ym[tt];
    }
    const float bs0 = bias[m_];
    const float bs1 = bias[32 + m_];
    f32x16 acc[8];

    if (wv < 3) conv2_kloop2<2>(pl, Bf, lane, q, ym, xm, mm, bs0, bs1, acc);
    else        conv2_kloop2<1>(pl, Bf, lane, q, ym, xm, mm, bs0, bs1, acc);
    __syncthreads();

    float* hx = (float*)pl;   // 12800 floats total; per-image stride 6400
    if (wv < 3) conv2_epi<2>(acc, hx, wv, m_, q);
    else        conv2_epi<1>(acc, hx, wv, m_, q);
    __syncthreads();

    for (int ii = tid; ii < 6272; ii += 256) {
        const int im = (ii >= 3136) ? 1 : 0;
        const int idx = ii - (im ? 3136 : 0);
        const float* hxi = hx + im * 6400;
        int oc2 = (idx * 2675) >> 17;
        int p = idx - 49 * oc2;
        int py = (p * 9363) >> 16;
        int px = p - 7 * py;
        float v = fmaxf(hxi[(2 * py * 7 + px) * 65 + oc2],
                        hxi[((2 * py + 1) * 7 + px) * 65 + oc2]);
        v = fmaxf(v, 0.f);
        unsigned short b1 = f2bf(v);
        unsigned short b2 = f2bf(v - bf2f(b1));
        size_t o = (size_t)n2 * 6272 + ii;
        out2[o] = b1; out2[ASTR + o] = b2;
    }
}

// ------- fc1 via MFMA (r14 proven) --------------------------------------------
__global__ __launch_bounds__(256) void fc1_mfma(const unsigned short* __restrict__ A2,
                                                const unsigned short* __restrict__ B2,
                                                float* __restrict__ part) {
    __shared__ unsigned short As[2][2048];
    __shared__ unsigned short Bs[2][2048];
    const int tid = threadIdx.x;
    const int n0 = blockIdx.x * 64, m0 = blockIdx.y * 64;
    const int koff = blockIdx.z * 448;
    const int lr = tid >> 2, g = tid & 3;
    const int slot = (((g ^ (lr >> 1)) & 3) << 3);
    const int lane = tid & 63, wv = tid >> 6;
    const int nq = wv & 1, mq = wv >> 1;
    const int q = lane >> 5, l31 = lane & 31;
    const int rA = 32 * nq + l31, rB = 32 * mq + l31;
    f32x16 acc;
    #pragma unroll
    for (int r = 0; r < 16; ++r) acc[r] = 0.f;

    for (int bk = 0; bk < 448; bk += 32) {
        const size_t ka = (size_t)(koff + bk + (g << 3));
        short8 av[2], bv[2];
        #pragma unroll
        for (int p = 0; p < 2; ++p) {
            av[p] = *(const short8*)(A2 + p * ASTR + (size_t)(n0 + lr) * 3136 + ka);
            bv[p] = *(const short8*)(B2 + p * BSTR + (size_t)(m0 + lr) * 3136 + ka);
        }
        __syncthreads();
        #pragma unroll
        for (int p = 0; p < 2; ++p) {
            *(short8*)&As[p][(lr << 5) + slot] = av[p];
            *(short8*)&Bs[p][(lr << 5) + slot] = bv[p];
        }
        __syncthreads();
        #pragma unroll
        for (int s2 = 0; s2 < 32; s2 += 16) {
            const int gg = (s2 + (q << 3)) >> 3;
            const int sa = (((gg ^ (rA >> 1)) & 3) << 3);
            const int sb = (((gg ^ (rB >> 1)) & 3) << 3);
            short8 a1 = *(const short8*)&As[0][(rA << 5) + sa];
            short8 a2 = *(const short8*)&As[1][(rA << 5) + sa];
            short8 b1 = *(const short8*)&Bs[0][(rB << 5) + sb];
            short8 b2 = *(const short8*)&Bs[1][(rB << 5) + sb];
            acc = __builtin_amdgcn_mfma_f32_32x32x16_bf16(a1, b1, acc, 0, 0, 0);
            acc = __builtin_amdgcn_mfma_f32_32x32x16_bf16(a1, b2, acc, 0, 0, 0);
            acc = __builtin_amdgcn_mfma_f32_32x32x16_bf16(a2, b1, acc, 0, 0, 0);
        }
    }
    float* pb = part + (size_t)blockIdx.z * NTOT * 512;
    #pragma unroll
    for (int reg = 0; reg < 16; ++reg) {
        int nn = n0 + 32 * nq + (reg & 3) + 8 * (reg >> 2) + 4 * q;
        int mmo = m0 + 32 * mq + l31;
        pb[(size_t)nn * 512 + mmo] = acc[reg];
    }
}

__global__ __launch_bounds__(256) void fc1_reduce(const float* __restrict__ part,
                                                  const float* __restrict__ bias,
                                                  float* __restrict__ lat,
                                                  unsigned short* __restrict__ lat2,
                                                  float* __restrict__ rep) {
    int idx = blockIdx.x * 256 + threadIdx.x;
    int m = idx & 511;
    float v = bias[m];
    #pragma unroll
    for (int kz = 0; kz < 7; ++kz) v += part[(size_t)kz * NTOT * 512 + idx];
    if (idx < BATCH * 512) {
        lat[idx] = v;
        unsigned short b1 = f2bf(v);
        lat2[idx] = b1;
        lat2[A2STR + idx] = f2bf(v - bf2f(b1));
    } else {
        rep[idx - BATCH * 512] = tanhf(v);
    }
}

// ------- fcn logits via MFMA (r17 proven) -------------------------------------
__global__ __launch_bounds__(256) void fcn_mfma(const unsigned short* __restrict__ A2,
                                                const unsigned short* __restrict__ B2,
                                                float* __restrict__ logits) {
    __shared__ unsigned short As[2][2048];
    __shared__ unsigned short Bs[2][2048];
    const int tid = threadIdx.x;
    const int n0 = blockIdx.x * 64, m0 = blockIdx.y * 64;
    const int lr = tid >> 2, g = tid & 3;
    const int slot = (((g ^ (lr >> 1)) & 3) << 3);
    const int lane = tid & 63, wv = tid >> 6;
    const int nq = wv & 1, mq = wv >> 1;
    const int q = lane >> 5, l31 = lane & 31;
    const int rA = 32 * nq + l31, rB = 32 * mq + l31;
    f32x16 acc;
    #pragma unroll
    for (int r = 0; r < 16; ++r) acc[r] = 0.f;

    for (int bk = 0; bk < 512; bk += 32) {
        const size_t ka = (size_t)(bk + (g << 3));
        short8 av[2], bv[2];
        #pragma unroll
        for (int p = 0; p < 2; ++p) {
            av[p] = *(const short8*)(A2 + p * A2STR + (size_t)(n0 + lr) * 512 + ka);
            bv[p] = *(const short8*)(B2 + p * W2STR + (size_t)(m0 + lr) * 512 + ka);
        }
        __syncthreads();
        #pragma unroll
        for (int p = 0; p < 2; ++p) {
            *(short8*)&As[p][(lr << 5) + slot] = av[p];
            *(short8*)&Bs[p][(lr << 5) + slot] = bv[p];
        }
        __syncthreads();
        #pragma unroll
        for (int s2 = 0; s2 < 32; s2 += 16) {
            const int gg = (s2 + (q << 3)) >> 3;
            const int sa = (((gg ^ (rA >> 1)) & 3) << 3);
            const int sb = (((gg ^ (rB >> 1)) & 3) << 3);
            short8 a1 = *(const short8*)&As[0][(rA << 5) + sa];
            short8 a2 = *(const short8*)&As[1][(rA << 5) + sa];
            short8 b1 = *(const short8*)&Bs[0][(rB << 5) + sb];
            short8 b2 = *(const short8*)&Bs[1][(rB << 5) + sb];
            acc = __builtin_amdgcn_mfma_f32_32x32x16_bf16(a1, b1, acc, 0, 0, 0);
            acc = __builtin_amdgcn_mfma_f32_32x32x16_bf16(a1, b2, acc, 0, 0, 0);
            acc = __builtin_amdgcn_mfma_f32_32x32x16_bf16(a2, b1, acc, 0, 0, 0);
        }
    }
    #pragma unroll
    for (int reg = 0; reg < 16; ++reg) {
        int nn = n0 + 32 * nq + (reg & 3) + 8 * (reg >> 2) + 4 * q;
        int mmo = m0 + 32 * mq + l31;
        logits[(size_t)nn * 128 + mmo] = acc[reg];
    }
}

__global__ __launch_bounds__(128) void fcn_softmax2(const float* __restrict__ logits,
                                                    const float* __restrict__ fb,
                                                    float* __restrict__ out) {
    const int b = blockIdx.x;
    const int j = threadIdx.x;
    __shared__ float red[128];
    float acc = logits[(size_t)b * 128 + j] + fb[j];
    red[j] = acc;
    __syncthreads();
    for (int off = 64; off >= 1; off >>= 1) {
        if (j < off) red[j] = fmaxf(red[j], red[j + off]);
        __syncthreads();
    }
    float mx = red[0];
    __syncthreads();
    float ex = expf(acc - mx);
    red[j] = ex;
    __syncthreads();
    for (int off = 64; off >= 1; off >>= 1) {
        if (j < off) red[j] += red[j + off];
        __syncthreads();
    }
    out[(size_t)b * 128 + j] = ex / red[0];
}

// ------- t v3 (r26): rho fused in (bit-exact replication of rho_kernel) -------
__global__ __launch_bounds__(256) void t_kernel(const float* __restrict__ rep,
                                                float* __restrict__ tT) {
    __shared__ float tile[64][65];
    __shared__ float red[256];
    const int tid = threadIdx.x;
    // --- inline rho: EXACT replica of r14 rho_kernel (same 256-thread strided
    // sum + same tree reduce + same divide) => bit-identical r0 in every block.
    {
        float s = 0.f;
        for (int i = tid; i < LABEL * LATENT; i += 256) s += rep[i];
        red[tid] = s;
        __syncthreads();
        for (int off = 128; off >= 1; off >>= 1) {
            if (tid < off) red[tid] += red[tid + off];
            __syncthreads();
        }
    }
    const float r0 = red[0] / (float)(LABEL * LATENT);
    const int i0 = blockIdx.x * 64, k0 = blockIdx.y * 64;
    const int tx = tid & 63, ty4 = tid >> 6;
    #pragma unroll
    for (int rr = 0; rr < 16; ++rr) {
        int kk = ty4 * 16 + rr;
        tile[kk][tx] = rep[(size_t)(k0 + kk) * 512 + i0 + tx];
    }
    __syncthreads();
    #pragma unroll
    for (int rr = 0; rr < 16; ++rr) {
        int ii = ty4 * 16 + rr;
        tT[(size_t)(i0 + ii) * 128 + k0 + tx] = tile[tx][ii] - r0;
    }
}

// ------- w_kernel v3 (r26): LDS-tiled, r14-EXACT per-output FP order ----------
__global__ __launch_bounds__(256) void w_kernel(const float* __restrict__ tT,
                                                float* __restrict__ w) {
    __shared__ float4 As[32][33];
    __shared__ float4 Bs[32][33];
    const int tid = threadIdx.x;
    const int i0 = blockIdx.x * 32, j0 = blockIdx.y * 32;
    for (int idx = tid; idx < 32 * 32; idx += 256) {
        int r = idx >> 5, qq = idx & 31;
        As[r][qq] = ((const float4*)(tT + (size_t)(i0 + r) * 128))[qq];
        Bs[r][qq] = ((const float4*)(tT + (size_t)(j0 + r) * 128))[qq];
    }
    __syncthreads();
    const int ty = tid >> 4, tx = tid & 15;   // 16x16 threads, 2x2 outputs each
    float acc[2][2] = {};
    for (int q = 0; q < 32; ++q) {
        float4 a4[2], b4[2];
        #pragma unroll
        for (int d = 0; d < 2; ++d) { a4[d] = As[ty * 2 + d][q]; b4[d] = Bs[tx * 2 + d][q]; }
        #pragma unroll
        for (int di = 0; di < 2; ++di)
        #pragma unroll
        for (int dj = 0; dj < 2; ++dj)
            acc[di][dj] += a4[di].x * b4[dj].x + a4[di].y * b4[dj].y +
                           a4[di].z * b4[dj].z + a4[di].w * b4[dj].w;
    }
    #pragma unroll
    for (int di = 0; di < 2; ++di)
    #pragma unroll
    for (int dj = 0; dj < 2; ++dj) {
        int i = i0 + ty * 2 + di, j = j0 + tx * 2 + dj;
        w[(size_t)i * 512 + j] = (i == j) ? 0.f : acc[di][dj] * (1.f / 128.f);
    }
}

// ------- hinit (r14 proven) ---------------------------------------------------
__global__ __launch_bounds__(256) void hinit(const float* __restrict__ lat,
                                             const float* __restrict__ w,
                                             float* __restrict__ hmat) {
    __shared__ float As[16][68];
    __shared__ float Bs[16][68];
    const int tid = threadIdx.x;
    const int n0 = blockIdx.x * 64, m0 = blockIdx.y * 64;
    const int lr = tid >> 2;
    const int lk = (tid & 3) * 4;
    const int ty = tid >> 4, tx = tid & 15;
    float c[4][4] = {};
    for (int k0 = 0; k0 < 512; k0 += 16) {
        float4 a4 = *(const float4*)(lat + (size_t)(n0 + lr) * 512 + k0 + lk);
        float4 b4 = *(const float4*)(w + (size_t)(m0 + lr) * 512 + k0 + lk);
        a4.x = tanhf(a4.x); a4.y = tanhf(a4.y); a4.z = tanhf(a4.z); a4.w = tanhf(a4.w);
        __syncthreads();
        As[lk + 0][lr] = a4.x; As[lk + 1][lr] = a4.y; As[lk + 2][lr] = a4.z; As[lk + 3][lr] = a4.w;
        Bs[lk + 0][lr] = b4.x; Bs[lk + 1][lr] = b4.y; Bs[lk + 2][lr] = b4.z; Bs[lk + 3][lr] = b4.w;
        __syncthreads();
        #pragma unroll
        for (int kk = 0; kk < 16; ++kk) {
            float av[4], bv[4];
            #pragma unroll
            for (int i = 0; i < 4; ++i) av[i] = As[kk][ty * 4 + i];
            #pragma unroll
            for (int j = 0; j < 4; ++j) bv[j] = Bs[kk][tx * 4 + j];
            #pragma unroll
            for (int i = 0; i < 4; ++i)
            #pragma unroll
            for (int j = 0; j < 4; ++j) c[i][j] += av[i] * bv[j];
        }
    }
    #pragma unroll
    for (int i = 0; i < 4; ++i)
    #pragma unroll
    for (int j = 0; j < 4; ++j)
        hmat[(size_t)(n0 + ty * 4 + i) * 512 + m0 + tx * 4 + j] = c[i][j];
}

// ------- clustering v3 (r18 proven): CB=1, incremental Hopfield ---------------
__device__ __forceinline__ float sgnf(float x) {
    return (x > 0.f) ? 1.f : ((x < 0.f) ? -1.f : 0.f);
}

__global__ __launch_bounds__(256) void clustering(const float* __restrict__ lat,
                                                  const float* __restrict__ hmat,
                                                  const float* __restrict__ w,
                                                  const float* __restrict__ rep,
                                                  float* __restrict__ out) {
    const int tid = threadIdx.x;
    const int row = blockIdx.x;
    __shared__ float mins[512];
    __shared__ float red[256];
    __shared__ float part_e[4];
    __shared__ int part_c[4];
    __shared__ float min_e_s;
    __shared__ int copyf_s;
    __shared__ int donef_s;
    __shared__ int cnt_s;
    __shared__ int jidx[512];
    __shared__ float jdel[512];
    const int i0 = 2 * tid, i1 = 2 * tid + 1;
    const int wave = tid >> 6, lane = tid & 63;

    float sm10, sm11, sm20, sm21, h0, h1;
    {
        sm10 = tanhf(lat[(size_t)row * 512 + i0]);
        sm11 = tanhf(lat[(size_t)row * 512 + i1]);
        sm20 = sm10; sm21 = sm11;
        h0 = hmat[(size_t)row * 512 + i0];
        h1 = hmat[(size_t)row * 512 + i1];
    }
    if (tid == 0) { min_e_s = INFINITY; donef_s = 0; cnt_s = 0; }
    __syncthreads();

    for (int k = 1; k <= 512; ++k) {
        float sn0 = fabsf(sm10) * sgnf(h0);
        float sn1 = fabsf(sm11) * sgnf(h1);
        int cy = (sn0 == sm20 && sn1 == sm21) ? 1 : 0;
        if (sn0 != sm10) {
            int p = atomicAdd(&cnt_s, 1);
            jidx[p] = i0; jdel[p] = sn0 - sm10;
        }
        if (sn1 != sm11) {
            int p = atomicAdd(&cnt_s, 1);
            jidx[p] = i1; jdel[p] = sn1 - sm11;
        }
        #pragma unroll
        for (int m = 32; m >= 1; m >>= 1) cy &= __shfl_xor(cy, m, 64);
        if (lane == 0) part_c[wave] = cy;
        __syncthreads();   // flip list complete

        {
            const int c = cnt_s;
            #pragma unroll 8
            for (int t = 0; t < c; ++t) {
                const int j = jidx[t];
                const float d = jdel[t];
                const float2 wvv = *(const float2*)(w + (size_t)j * 512 + i0);
                h0 = fmaf(d, wvv.x, h0);
                h1 = fmaf(d, wvv.y, h1);
            }
        }
        float ep = sn0 * h0 + sn1 * h1;
        #pragma unroll
        for (int m = 32; m >= 1; m >>= 1) ep += __shfl_xor(ep, m, 64);
        if (lane == 0) part_e[wave] = ep;
        __syncthreads();

        if (tid == 0) {
            float e = -(part_e[0] + part_e[1] + part_e[2] + part_e[3]);
            int better = e < min_e_s;
            if (better) min_e_s = e;
            copyf_s = better;
            int fl = part_c[0] & part_c[1] & part_c[2] & part_c[3];
            int fixedp = (cnt_s == 0);
            int cyc = (k >= 2) && fl;
            if (fixedp || cyc) donef_s = 1;
            cnt_s = 0;
        }
        __syncthreads();

        if (copyf_s) { mins[i0] = sn0; mins[i1] = sn1; }
        sm20 = sm10; sm21 = sm11;
        sm10 = sn0;  sm11 = sn1;
        if (donef_s) break;
    }
    __syncthreads();

    const int j = tid & 127, half = tid >> 7;
    {
        const float4* rr = (const float4*)(rep + (size_t)j * 512 + half * 256);
        const float4* ms = (const float4*)(&mins[half * 256]);
        float p = 0.f;
        #pragma unroll 8
        for (int q = 0; q < 64; ++q) {
            float4 rv = rr[q], mv = ms[q];
            p += rv.x * mv.x + rv.y * mv.y + rv.z * mv.z + rv.w * mv.w;
        }
        red[tid] = p;
        __syncthreads();
        float v = 0.f;
        if (tid < 128) { v = fabsf(red[tid] + red[tid + 128]); red[tid] = v; }
        __syncthreads();
        for (int off = 64; off >= 1; off >>= 1) {
            if (tid < off) red[tid] = fmaxf(red[tid], red[tid + off]);
            __syncthreads();
        }
        float mx = red[0];
        __syncthreads();
        float ex = 0.f;
        if (tid < 128) { ex = expf(v - mx); red[tid] = ex; }
        __syncthreads();
        for (int off = 64; off >= 1; off >>= 1) {
            if (tid < off) red[tid] += red[tid + off];
            __syncthreads();
        }
        if (tid < 128) out[(size_t)row * 128 + tid] = ex / red[0];
    }
}

extern "C" void kernel_launch(void* const* d_in, const int* in_sizes, int n_in,
                              void* d_out, int out_size, void* d_ws, size_t ws_size,
                              hipStream_t stream) {
    const float* image = (const float*)d_in[0];
    const float* limg  = (const float*)d_in[1];
    const float* c1w   = (const float*)d_in[2];
    const float* c1b   = (const float*)d_in[3];
    const float* c2w   = (const float*)d_in[4];
    const float* c2b   = (const float*)d_in[5];
    const float* f1w   = (const float*)d_in[6];
    const float* f1b   = (const float*)d_in[7];
    const float* fnw   = (const float*)d_in[8];
    const float* fnb   = (const float*)d_in[9];
    float* out = (float*)d_out;
    float* ws  = (float*)d_ws;

    unsigned short* o1b  = (unsigned short*)ws;        // (r27: region now unused)
    unsigned short* out2 = o1b + (size_t)NTOT * 12800; // 2*ASTR bf16
    float* lat  = (float*)(out2 + 2 * ASTR);           // 1024*512
    float* rep  = lat + (size_t)BATCH * 512;           // 128*512
    float* tT   = rep + (size_t)LABEL * 512;           // 512*128
    float* wmat = tT + (size_t)512 * 128;              // 512*512
    float* rho  = wmat + (size_t)512 * 512;            // 1 (+pad, kept for layout)
    unsigned short* Bw2   = (unsigned short*)(rho + 16);   // 2*BSTR bf16
    unsigned short* Bfrag = Bw2 + 2 * BSTR;                // 102,400 bf16
    float* hmat = (float*)(Bfrag + 102400);            // 1024*512 f32
    unsigned short* lat2 = (unsigned short*)(hmat + A2STR);  // 2*A2STR bf16
    unsigned short* fnw2 = lat2 + 2 * A2STR;           // 2*W2STR bf16
    float* logits = (float*)(fnw2 + 2 * W2STR);        // 1024*128 f32
    float* part = (float*)ws;                          // alias o1b region (unused)

    const int prep_total = 102400 + 512 * 3136 + 128 * 512;
    hipLaunchKernelGGL(prep, dim3((prep_total + 255) / 256), dim3(256), 0, stream,
                       c2w, f1w, fnw, Bfrag, Bw2, fnw2);
    hipLaunchKernelGGL(conv12_mfma, dim3(NTOT / 2), dim3(256), 0, stream,
                       image, limg, c1w, c1b, Bfrag, c2b, out2);
    hipLaunchKernelGGL(fc1_mfma, dim3(NTOT / 64, 512 / 64, 7), dim3(256), 0, stream,
                       out2, Bw2, part);
    hipLaunchKernelGGL(fc1_reduce, dim3(NTOT * 512 / 256), dim3(256), 0, stream,
                       part, f1b, lat, lat2, rep);
    hipLaunchKernelGGL(fcn_mfma, dim3(16, 2), dim3(256), 0, stream, lat2, fnw2, logits);
    hipLaunchKernelGGL(fcn_softmax2, dim3(BATCH), dim3(128), 0, stream, logits, fnb,
                       out + (size_t)BATCH * LABEL);
    hipLaunchKernelGGL(t_kernel, dim3(8, 2), dim3(256), 0, stream, rep, tT);
    hipLaunchKernelGGL(w_kernel, dim3(16, 16), dim3(256), 0, stream, tT, wmat);
    hipLaunchKernelGGL(hinit, dim3(BATCH / 64, 512 / 64), dim3(256), 0, stream, lat, wmat, hmat);
    hipLaunchKernelGGL(clustering, dim3(BATCH), dim3(256), 0, stream,
                       lat, hmat, wmat, rep, out);
}

// Round 7
// 380.257 us; speedup vs baseline: 1.0096x; 1.0096x over previous
//
#include <hip/hip_runtime.h>
#include <hip/hip_bf16.h>
#include <math.h>

#define BATCH 1024
#define LABEL 128
#define LATENT 512
#define NTOT 1152  // 1024 + 128

typedef short short8 __attribute__((ext_vector_type(8)));
typedef float f32x16 __attribute__((ext_vector_type(16)));

__device__ __forceinline__ unsigned short f2bf(float f) {
    __hip_bfloat16 h = __float2bfloat16(f);
    return *(unsigned short*)&h;
}
__device__ __forceinline__ float bf2f(unsigned short u) {
    __hip_bfloat16 h; *(unsigned short*)&h = u;
    return __bfloat162float(h);
}

#define BSTR ((size_t)512 * 3136)
#define ASTR ((size_t)NTOT * 3136)
#define A2STR ((size_t)BATCH * 512)
#define W2STR ((size_t)LABEL * 512)

// conv1 output layout (per image): 2 bf16 planes of 6400 ushorts.
// Plane = 196 compact pixels (14x14) x 32ch, granule = 64B, slot-swizzled:
// off = p*32 + (((oc>>3) ^ (p>>1)) & 3)*8 + (oc&7).  Granules 196..199 zeroed.
//
// NUMERICS RULE (r15): w_kernel/rho keep r14-exact op order (Hopfield sign
// cascades). COVERAGE RULE (r16): conv1 writes all 196 pixels (xh loop).
// r19 lesson: do not add kernels to the tail (launch+roundtrip > savings).
// r22/r23: conv2 v9.1 = 2 img/block dual-ocT waves, 83.3us PROVEN OPTIMUM.
// r24 (more occ) / r25 (manual pipeline) / r27 (conv1 fusion) — all WORSE.
// r27 lesson: fusion drags high-occupancy conv1 down to conv2's 2 blk/CU.
// r26: rho fused into t_kernel; w_kernel LDS-tiled. 376.8us BEST.
// r28: revert conv1/conv2 to r26. DELETE t_kernel: w_kernel v4 stages
// rep directly into the same LDS values (As_f[r][k] = rep[k][i0+r]-r0) with
// in-block rho replica. Compute loop untouched -> bit-exact. -1 launch,
// -256KB roundtrip.

// ------- conv1 v3 (r17 proven) ------------------------------------------------
__global__ __launch_bounds__(256) void conv1_pool(const float* __restrict__ image,
                                                  const float* __restrict__ limg,
                                                  const float* __restrict__ wt,
                                                  const float* __restrict__ bias,
                                                  unsigned short* __restrict__ o1b) {
    const int n = blockIdx.x;
    const float* in = (n < BATCH) ? (image + (size_t)n * 784)
                                  : (limg + (size_t)(n - BATCH) * 784);
    __shared__ float pin[32][32];
    __shared__ float wts[32 * 25];
    const int tid = threadIdx.x;
    unsigned short* ob = o1b + (size_t)n * 12800;
    for (int i = tid; i < 256; i += 256) {
        int pl_ = i >> 7, r = i & 127;
        ob[pl_ * 6400 + 6272 + r] = 0;
    }
    for (int idx = tid; idx < 32 * 32; idx += 256) ((float*)pin)[idx] = 0.f;
    __syncthreads();
    for (int idx = tid; idx < 784; idx += 256) {
        int y = idx / 28, x = idx % 28;
        pin[y + 2][x + 2] = in[idx];
    }
    for (int idx = tid; idx < 800; idx += 256) wts[idx] = wt[idx];
    __syncthreads();
    const int oc = tid & 31;
    float wk[25];
    #pragma unroll
    for (int k = 0; k < 25; ++k) wk[k] = wts[oc * 25 + k];
    const float b = bias[oc];
    const int slot_lo = (oc & 7);
    const int gq = oc >> 3;
    for (int it = 0; it < 2; ++it) {
        const int py = (tid >> 5) + it * 8;
        if (py >= 14) continue;
        #pragma unroll
        for (int xh = 0; xh < 2; ++xh) {
            const int acol = xh ? 12 : 0;
            const int off = xh ? 2 : 0;
            float a0[14], a1[14];
            #pragma unroll
            for (int c = 0; c < 14; ++c) { a0[c] = b; a1[c] = b; }
            #pragma unroll
            for (int t = 0; t < 6; ++t) {
                float row[20];
                const float4* rp = (const float4*)&pin[2 * py + t][acol];
                #pragma unroll
                for (int v = 0; v < 5; ++v) {
                    float4 f = rp[v];
                    row[4 * v] = f.x; row[4 * v + 1] = f.y;
                    row[4 * v + 2] = f.z; row[4 * v + 3] = f.w;
                }
                if (t < 5) {
                    #pragma unroll
                    for (int kx = 0; kx < 5; ++kx) {
                        float w0 = wk[t * 5 + kx];
                        #pragma unroll
                        for (int c = 0; c < 14; ++c)
                            a0[c] = fmaf(row[c + kx + off], w0, a0[c]);
                    }
                }
                if (t >= 1) {
                    #pragma unroll
                    for (int kx = 0; kx < 5; ++kx) {
                        float w1 = wk[(t - 1) * 5 + kx];
                        #pragma unroll
                        for (int c = 0; c < 14; ++c)
                            a1[c] = fmaf(row[c + kx + off], w1, a1[c]);
                    }
                }
            }
            #pragma unroll
            for (int px = 0; px < 7; ++px) {
                float v = fmaxf(fmaxf(a0[2 * px], a0[2 * px + 1]),
                                fmaxf(a1[2 * px], a1[2 * px + 1]));
                v = fmaxf(v, 0.f);
                unsigned short b1 = f2bf(v);
                unsigned short b2 = f2bf(v - bf2f(b1));
                int p = py * 14 + 7 * xh + px;
                int offo = p * 32 + (((gq ^ (p >> 1)) & 3) << 3) + slot_lo;
                ob[offo] = b1; ob[6400 + offo] = b2;
            }
        }
    }
}

// ------- merged prep (r17 proven) ---------------------------------------------
__global__ __launch_bounds__(256) void prep(const float* __restrict__ c2w,
                                            const float* __restrict__ f1w,
                                            const float* __restrict__ fnw,
                                            unsigned short* __restrict__ Bf,
                                            unsigned short* __restrict__ Bw2,
                                            unsigned short* __restrict__ Bn2) {
    int idx = blockIdx.x * 256 + threadIdx.x;
    if (idx < 102400) {
        int j = idx & 7, lane = (idx >> 3) & 63, ocT = (idx >> 9) & 1, s = idx >> 10;
        int q = lane >> 5, nn = lane & 31;
        int k = 16 * s + 8 * q + j;
        int tap = k >> 5, ic = k & 31;
        int oc = 32 * ocT + nn;
        float v = c2w[oc * 800 + ic * 25 + tap];
        unsigned short b1 = f2bf(v);
        unsigned short b2 = f2bf(v - bf2f(b1));
        size_t base = ((size_t)(s * 2 + ocT) * 2) * 512 + lane * 8 + j;
        Bf[base] = b1; Bf[base + 512] = b2;
        return;
    }
    int i2 = idx - 102400;
    if (i2 < 512 * 3136) {
        float v = f1w[i2];
        unsigned short b1 = f2bf(v);
        unsigned short b2 = f2bf(v - bf2f(b1));
        Bw2[i2] = b1; Bw2[BSTR + i2] = b2;
        return;
    }
    int i3 = i2 - 512 * 3136;
    if (i3 >= 128 * 512) return;
    float v = fnw[i3];
    unsigned short b1 = f2bf(v);
    unsigned short b2 = f2bf(v - bf2f(b1));
    Bn2[i3] = b1; Bn2[W2STR + i3] = b2;
}

// ------- conv2 via MFMA v9.1 (r23 PROVEN, verbatim): 2 img/block --------------
template<int NT>
__device__ __forceinline__ void conv2_kloop2(const unsigned short* __restrict__ pl,
                                             const unsigned short* __restrict__ Bf,
                                             const int lane, const int q,
                                             const int* __restrict__ ym,
                                             const int* __restrict__ xm,
                                             const int* __restrict__ mm,
                                             const float bs0, const float bs1,
                                             f32x16* __restrict__ acc) {
    #pragma unroll
    for (int im = 0; im < 2; ++im)
    #pragma unroll
    for (int oc = 0; oc < 2; ++oc) {
        const float bs = oc ? bs1 : bs0;
        #pragma unroll
        for (int tt = 0; tt < NT; ++tt)
        #pragma unroll
        for (int r = 0; r < 16; ++r) acc[(im * 2 + oc) * NT + tt][r] = bs;
    }
    for (int s = 0; s < 50; ++s) {
        const unsigned short* bp = Bf + (size_t)s * 2048 + lane * 8;
        short8 b1[2], b2[2];
        b1[0] = *(const short8*)(bp);
        b2[0] = *(const short8*)(bp + 512);
        b1[1] = *(const short8*)(bp + 1024);
        b2[1] = *(const short8*)(bp + 1536);
        const int kb = 16 * s + 8 * q;
        const int tap = kb >> 5, g = (kb & 31) >> 3;
        const int ky = (tap * 13) >> 6;       // exact /5 for tap<25
        const int kx = tap - ky * 5;
        const int iyk = ky - 2, ixk = kx - 2;
        const int pq2 = iyk * 14 + ixk;
        int addr[NT];
        #pragma unroll
        for (int tt = 0; tt < NT; ++tt) {
            int iy = ym[tt] + iyk, ix = xm[tt] + ixk;
            int valid = ((unsigned)iy < 14u) & ((unsigned)ix < 14u);
            int cpt = valid ? (mm[tt] + pq2) : 196;
            addr[tt] = cpt * 32 + (((g ^ (cpt >> 1)) & 3) << 3);
        }
        short8 a1[2][NT], a2[2][NT];
        #pragma unroll
        for (int im = 0; im < 2; ++im) {
            const unsigned short* pli = pl + im * 12800;
            #pragma unroll
            for (int tt = 0; tt < NT; ++tt) {
                a1[im][tt] = *(const short8*)(pli + addr[tt]);
                a2[im][tt] = *(const short8*)(pli + 6400 + addr[tt]);
            }
        }
        #pragma unroll
        for (int im = 0; im < 2; ++im)
        #pragma unroll
        for (int oc = 0; oc < 2; ++oc)
        #pragma unroll
        for (int tt = 0; tt < NT; ++tt) {
            f32x16 a = acc[(im * 2 + oc) * NT + tt];
            a = __builtin_amdgcn_mfma_f32_32x32x16_bf16(a1[im][tt], b1[oc], a, 0, 0, 0);
            a = __builtin_amdgcn_mfma_f32_32x32x16_bf16(a1[im][tt], b2[oc], a, 0, 0, 0);
            a = __builtin_amdgcn_mfma_f32_32x32x16_bf16(a2[im][tt], b1[oc], a, 0, 0, 0);
            acc[(im * 2 + oc) * NT + tt] = a;
        }
    }
}

template<int NT>
__device__ __forceinline__ void conv2_epi(const f32x16* __restrict__ acc,
                                          float* __restrict__ hx,
                                          const int wv, const int m_, const int q) {
    #pragma unroll
    for (int im = 0; im < 2; ++im) {
        float* hxi = hx + im * 6400;
        #pragma unroll
        for (int oc = 0; oc < 2; ++oc) {
            const int occ = 32 * oc + m_;
            #pragma unroll
            for (int tt = 0; tt < NT; ++tt)
            #pragma unroll
            for (int e = 0; e < 8; ++e) {
                const int reg = 2 * e;
                const int r = (reg & 3) + 8 * (reg >> 2) + 4 * q;
                const int m = 32 * (2 * wv + tt) + r;
                if (m < 196) {
                    float xm2 = fmaxf(acc[(im * 2 + oc) * NT + tt][reg],
                                      acc[(im * 2 + oc) * NT + tt][reg + 1]);
                    int y = (m * 2341) >> 15;
                    int px = (m - 14 * y) >> 1;
                    hxi[(y * 7 + px) * 65 + occ] = xm2;
                }
            }
        }
    }
}

__global__ __launch_bounds__(256, 2) void conv2_mfma(const unsigned short* __restrict__ o1b,
                                                     const unsigned short* __restrict__ Bf,
                                                     const float* __restrict__ bias,
                                                     unsigned short* __restrict__ out2) {
    const int n2 = blockIdx.x;            // image pair (2*n2, 2*n2+1)
    __shared__ __align__(16) unsigned short pl[2 * 12800];
    const int tid = threadIdx.x;
    const int lane = tid & 63, wv = tid >> 6;   // wv = m-tile pair index

    {
        const float4* src = (const float4*)(o1b + (size_t)n2 * 25600);
        float4* dst = (float4*)pl;
        for (int i = tid; i < 3200; i += 256) dst[i] = src[i];
    }
    __syncthreads();

    const int m_ = lane & 31, q = lane >> 5;
    int ym[2], xm[2], mm[2];
    #pragma unroll
    for (int tt = 0; tt < 2; ++tt) {
        int t = 2 * wv + tt;
        if (t > 6) t = 6;               // wv=3,tt=1 dummy (kloop<1> never uses it)
        int m = 32 * t + m_;
        mm[tt] = m;
        ym[tt] = m / 14;
        xm[tt] = m - 14 * ym[tt];
    }
    const float bs0 = bias[m_];
    const float bs1 = bias[32 + m_];
    f32x16 acc[8];

    if (wv < 3) conv2_kloop2<2>(pl, Bf, lane, q, ym, xm, mm, bs0, bs1, acc);
    else        conv2_kloop2<1>(pl, Bf, lane, q, ym, xm, mm, bs0, bs1, acc);
    __syncthreads();

    float* hx = (float*)pl;   // 12800 floats total; per-image stride 6400
    if (wv < 3) conv2_epi<2>(acc, hx, wv, m_, q);
    else        conv2_epi<1>(acc, hx, wv, m_, q);
    __syncthreads();

    for (int ii = tid; ii < 6272; ii += 256) {
        const int im = (ii >= 3136) ? 1 : 0;
        const int idx = ii - (im ? 3136 : 0);
        const float* hxi = hx + im * 6400;
        int oc2 = (idx * 2675) >> 17;
        int p = idx - 49 * oc2;
        int py = (p * 9363) >> 16;
        int px = p - 7 * py;
        float v = fmaxf(hxi[(2 * py * 7 + px) * 65 + oc2],
                        hxi[((2 * py + 1) * 7 + px) * 65 + oc2]);
        v = fmaxf(v, 0.f);
        unsigned short b1 = f2bf(v);
        unsigned short b2 = f2bf(v - bf2f(b1));
        size_t o = (size_t)n2 * 6272 + ii;
        out2[o] = b1; out2[ASTR + o] = b2;
    }
}

// ------- fc1 via MFMA (r14 proven) --------------------------------------------
__global__ __launch_bounds__(256) void fc1_mfma(const unsigned short* __restrict__ A2,
                                                const unsigned short* __restrict__ B2,
                                                float* __restrict__ part) {
    __shared__ unsigned short As[2][2048];
    __shared__ unsigned short Bs[2][2048];
    const int tid = threadIdx.x;
    const int n0 = blockIdx.x * 64, m0 = blockIdx.y * 64;
    const int koff = blockIdx.z * 448;
    const int lr = tid >> 2, g = tid & 3;
    const int slot = (((g ^ (lr >> 1)) & 3) << 3);
    const int lane = tid & 63, wv = tid >> 6;
    const int nq = wv & 1, mq = wv >> 1;
    const int q = lane >> 5, l31 = lane & 31;
    const int rA = 32 * nq + l31, rB = 32 * mq + l31;
    f32x16 acc;
    #pragma unroll
    for (int r = 0; r < 16; ++r) acc[r] = 0.f;

    for (int bk = 0; bk < 448; bk += 32) {
        const size_t ka = (size_t)(koff + bk + (g << 3));
        short8 av[2], bv[2];
        #pragma unroll
        for (int p = 0; p < 2; ++p) {
            av[p] = *(const short8*)(A2 + p * ASTR + (size_t)(n0 + lr) * 3136 + ka);
            bv[p] = *(const short8*)(B2 + p * BSTR + (size_t)(m0 + lr) * 3136 + ka);
        }
        __syncthreads();
        #pragma unroll
        for (int p = 0; p < 2; ++p) {
            *(short8*)&As[p][(lr << 5) + slot] = av[p];
            *(short8*)&Bs[p][(lr << 5) + slot] = bv[p];
        }
        __syncthreads();
        #pragma unroll
        for (int s2 = 0; s2 < 32; s2 += 16) {
            const int gg = (s2 + (q << 3)) >> 3;
            const int sa = (((gg ^ (rA >> 1)) & 3) << 3);
            const int sb = (((gg ^ (rB >> 1)) & 3) << 3);
            short8 a1 = *(const short8*)&As[0][(rA << 5) + sa];
            short8 a2 = *(const short8*)&As[1][(rA << 5) + sa];
            short8 b1 = *(const short8*)&Bs[0][(rB << 5) + sb];
            short8 b2 = *(const short8*)&Bs[1][(rB << 5) + sb];
            acc = __builtin_amdgcn_mfma_f32_32x32x16_bf16(a1, b1, acc, 0, 0, 0);
            acc = __builtin_amdgcn_mfma_f32_32x32x16_bf16(a1, b2, acc, 0, 0, 0);
            acc = __builtin_amdgcn_mfma_f32_32x32x16_bf16(a2, b1, acc, 0, 0, 0);
        }
    }
    float* pb = part + (size_t)blockIdx.z * NTOT * 512;
    #pragma unroll
    for (int reg = 0; reg < 16; ++reg) {
        int nn = n0 + 32 * nq + (reg & 3) + 8 * (reg >> 2) + 4 * q;
        int mmo = m0 + 32 * mq + l31;
        pb[(size_t)nn * 512 + mmo] = acc[reg];
    }
}

__global__ __launch_bounds__(256) void fc1_reduce(const float* __restrict__ part,
                                                  const float* __restrict__ bias,
                                                  float* __restrict__ lat,
                                                  unsigned short* __restrict__ lat2,
                                                  float* __restrict__ rep) {
    int idx = blockIdx.x * 256 + threadIdx.x;
    int m = idx & 511;
    float v = bias[m];
    #pragma unroll
    for (int kz = 0; kz < 7; ++kz) v += part[(size_t)kz * NTOT * 512 + idx];
    if (idx < BATCH * 512) {
        lat[idx] = v;
        unsigned short b1 = f2bf(v);
        lat2[idx] = b1;
        lat2[A2STR + idx] = f2bf(v - bf2f(b1));
    } else {
        rep[idx - BATCH * 512] = tanhf(v);
    }
}

// ------- fcn logits via MFMA (r17 proven) -------------------------------------
__global__ __launch_bounds__(256) void fcn_mfma(const unsigned short* __restrict__ A2,
                                                const unsigned short* __restrict__ B2,
                                                float* __restrict__ logits) {
    __shared__ unsigned short As[2][2048];
    __shared__ unsigned short Bs[2][2048];
    const int tid = threadIdx.x;
    const int n0 = blockIdx.x * 64, m0 = blockIdx.y * 64;
    const int lr = tid >> 2, g = tid & 3;
    const int slot = (((g ^ (lr >> 1)) & 3) << 3);
    const int lane = tid & 63, wv = tid >> 6;
    const int nq = wv & 1, mq = wv >> 1;
    const int q = lane >> 5, l31 = lane & 31;
    const int rA = 32 * nq + l31, rB = 32 * mq + l31;
    f32x16 acc;
    #pragma unroll
    for (int r = 0; r < 16; ++r) acc[r] = 0.f;

    for (int bk = 0; bk < 512; bk += 32) {
        const size_t ka = (size_t)(bk + (g << 3));
        short8 av[2], bv[2];
        #pragma unroll
        for (int p = 0; p < 2; ++p) {
            av[p] = *(const short8*)(A2 + p * A2STR + (size_t)(n0 + lr) * 512 + ka);
            bv[p] = *(const short8*)(B2 + p * W2STR + (size_t)(m0 + lr) * 512 + ka);
        }
        __syncthreads();
        #pragma unroll
        for (int p = 0; p < 2; ++p) {
            *(short8*)&As[p][(lr << 5) + slot] = av[p];
            *(short8*)&Bs[p][(lr << 5) + slot] = bv[p];
        }
        __syncthreads();
        #pragma unroll
        for (int s2 = 0; s2 < 32; s2 += 16) {
            const int gg = (s2 + (q << 3)) >> 3;
            const int sa = (((gg ^ (rA >> 1)) & 3) << 3);
            const int sb = (((gg ^ (rB >> 1)) & 3) << 3);
            short8 a1 = *(const short8*)&As[0][(rA << 5) + sa];
            short8 a2 = *(const short8*)&As[1][(rA << 5) + sa];
            short8 b1 = *(const short8*)&Bs[0][(rB << 5) + sb];
            short8 b2 = *(const short8*)&Bs[1][(rB << 5) + sb];
            acc = __builtin_amdgcn_mfma_f32_32x32x16_bf16(a1, b1, acc, 0, 0, 0);
            acc = __builtin_amdgcn_mfma_f32_32x32x16_bf16(a1, b2, acc, 0, 0, 0);
            acc = __builtin_amdgcn_mfma_f32_32x32x16_bf16(a2, b1, acc, 0, 0, 0);
        }
    }
    #pragma unroll
    for (int reg = 0; reg < 16; ++reg) {
        int nn = n0 + 32 * nq + (reg & 3) + 8 * (reg >> 2) + 4 * q;
        int mmo = m0 + 32 * mq + l31;
        logits[(size_t)nn * 128 + mmo] = acc[reg];
    }
}

__global__ __launch_bounds__(128) void fcn_softmax2(const float* __restrict__ logits,
                                                    const float* __restrict__ fb,
                                                    float* __restrict__ out) {
    const int b = blockIdx.x;
    const int j = threadIdx.x;
    __shared__ float red[128];
    float acc = logits[(size_t)b * 128 + j] + fb[j];
    red[j] = acc;
    __syncthreads();
    for (int off = 64; off >= 1; off >>= 1) {
        if (j < off) red[j] = fmaxf(red[j], red[j + off]);
        __syncthreads();
    }
    float mx = red[0];
    __syncthreads();
    float ex = expf(acc - mx);
    red[j] = ex;
    __syncthreads();
    for (int off = 64; off >= 1; off >>= 1) {
        if (j < off) red[j] += red[j + off];
        __syncthreads();
    }
    out[(size_t)b * 128 + j] = ex / red[0];
}

// ------- w_kernel v4 (r28): direct-from-rep, rho replica, bit-exact -----------
// As_f[r][k] must equal tT[i0+r][k] = rep[k][i0+r] - r0. float4 view As[r][qq]
// reads float offset r*132+4qq; element k lands at r*132+k -> stage scalar.
// Compute loop identical to v3 -> identical FP results.
__global__ __launch_bounds__(256) void w_kernel(const float* __restrict__ rep,
                                                float* __restrict__ w) {
    __shared__ float4 As[32][33];
    __shared__ float4 Bs[32][33];
    __shared__ float red[256];
    const int tid = threadIdx.x;
    // inline rho: EXACT replica of r14 rho_kernel reduce.
    {
        float s = 0.f;
        for (int i = tid; i < LABEL * LATENT; i += 256) s += rep[i];
        red[tid] = s;
        __syncthreads();
        for (int off = 128; off >= 1; off >>= 1) {
            if (tid < off) red[tid] += red[tid + off];
            __syncthreads();
        }
    }
    const float r0 = red[0] / (float)(LABEL * LATENT);
    const int i0 = blockIdx.x * 32, j0 = blockIdx.y * 32;
    float* Asf = (float*)As;   // row stride 132 floats
    float* Bsf = (float*)Bs;
    const int tx = tid & 31, ty = tid >> 5;   // 32 cols x 8 rows per pass
    for (int pass = 0; pass < 16; ++pass) {
        const int k = pass * 8 + ty;
        Asf[tx * 132 + k] = rep[(size_t)k * 512 + i0 + tx] - r0;
        Bsf[tx * 132 + k] = rep[(size_t)k * 512 + j0 + tx] - r0;
    }
    __syncthreads();
    const int ty2 = tid >> 4, tx2 = tid & 15;   // 16x16 threads, 2x2 outputs each
    float acc[2][2] = {};
    for (int q = 0; q < 32; ++q) {
        float4 a4[2], b4[2];
        #pragma unroll
        for (int d = 0; d < 2; ++d) { a4[d] = As[ty2 * 2 + d][q]; b4[d] = Bs[tx2 * 2 + d][q]; }
        #pragma unroll
        for (int di = 0; di < 2; ++di)
        #pragma unroll
        for (int dj = 0; dj < 2; ++dj)
            acc[di][dj] += a4[di].x * b4[dj].x + a4[di].y * b4[dj].y +
                           a4[di].z * b4[dj].z + a4[di].w * b4[dj].w;
    }
    #pragma unroll
    for (int di = 0; di < 2; ++di)
    #pragma unroll
    for (int dj = 0; dj < 2; ++dj) {
        int i = i0 + ty2 * 2 + di, j = j0 + tx2 * 2 + dj;
        w[(size_t)i * 512 + j] = (i == j) ? 0.f : acc[di][dj] * (1.f / 128.f);
    }
}

// ------- hinit (r14 proven) ---------------------------------------------------
__global__ __launch_bounds__(256) void hinit(const float* __restrict__ lat,
                                             const float* __restrict__ w,
                                             float* __restrict__ hmat) {
    __shared__ float As[16][68];
    __shared__ float Bs[16][68];
    const int tid = threadIdx.x;
    const int n0 = blockIdx.x * 64, m0 = blockIdx.y * 64;
    const int lr = tid >> 2;
    const int lk = (tid & 3) * 4;
    const int ty = tid >> 4, tx = tid & 15;
    float c[4][4] = {};
    for (int k0 = 0; k0 < 512; k0 += 16) {
        float4 a4 = *(const float4*)(lat + (size_t)(n0 + lr) * 512 + k0 + lk);
        float4 b4 = *(const float4*)(w + (size_t)(m0 + lr) * 512 + k0 + lk);
        a4.x = tanhf(a4.x); a4.y = tanhf(a4.y); a4.z = tanhf(a4.z); a4.w = tanhf(a4.w);
        __syncthreads();
        As[lk + 0][lr] = a4.x; As[lk + 1][lr] = a4.y; As[lk + 2][lr] = a4.z; As[lk + 3][lr] = a4.w;
        Bs[lk + 0][lr] = b4.x; Bs[lk + 1][lr] = b4.y; Bs[lk + 2][lr] = b4.z; Bs[lk + 3][lr] = b4.w;
        __syncthreads();
        #pragma unroll
        for (int kk = 0; kk < 16; ++kk) {
            float av[4], bv[4];
            #pragma unroll
            for (int i = 0; i < 4; ++i) av[i] = As[kk][ty * 4 + i];
            #pragma unroll
            for (int j = 0; j < 4; ++j) bv[j] = Bs[kk][tx * 4 + j];
            #pragma unroll
            for (int i = 0; i < 4; ++i)
            #pragma unroll
            for (int j = 0; j < 4; ++j) c[i][j] += av[i] * bv[j];
        }
    }
    #pragma unroll
    for (int i = 0; i < 4; ++i)
    #pragma unroll
    for (int j = 0; j < 4; ++j)
        hmat[(size_t)(n0 + ty * 4 + i) * 512 + m0 + tx * 4 + j] = c[i][j];
}

// ------- clustering v3 (r18 proven): CB=1, incremental Hopfield ---------------
__device__ __forceinline__ float sgnf(float x) {
    return (x > 0.f) ? 1.f : ((x < 0.f) ? -1.f : 0.f);
}

__global__ __launch_bounds__(256) void clustering(const float* __restrict__ lat,
                                                  const float* __restrict__ hmat,
                                                  const float* __restrict__ w,
                                                  const float* __restrict__ rep,
                                                  float* __restrict__ out) {
    const int tid = threadIdx.x;
    const int row = blockIdx.x;
    __shared__ float mins[512];
    __shared__ float red[256];
    __shared__ float part_e[4];
    __shared__ int part_c[4];
    __shared__ float min_e_s;
    __shared__ int copyf_s;
    __shared__ int donef_s;
    __shared__ int cnt_s;
    __shared__ int jidx[512];
    __shared__ float jdel[512];
    const int i0 = 2 * tid, i1 = 2 * tid + 1;
    const int wave = tid >> 6, lane = tid & 63;

    float sm10, sm11, sm20, sm21, h0, h1;
    {
        sm10 = tanhf(lat[(size_t)row * 512 + i0]);
        sm11 = tanhf(lat[(size_t)row * 512 + i1]);
        sm20 = sm10; sm21 = sm11;
        h0 = hmat[(size_t)row * 512 + i0];
        h1 = hmat[(size_t)row * 512 + i1];
    }
    if (tid == 0) { min_e_s = INFINITY; donef_s = 0; cnt_s = 0; }
    __syncthreads();

    for (int k = 1; k <= 512; ++k) {
        float sn0 = fabsf(sm10) * sgnf(h0);
        float sn1 = fabsf(sm11) * sgnf(h1);
        int cy = (sn0 == sm20 && sn1 == sm21) ? 1 : 0;
        if (sn0 != sm10) {
            int p = atomicAdd(&cnt_s, 1);
            jidx[p] = i0; jdel[p] = sn0 - sm10;
        }
        if (sn1 != sm11) {
            int p = atomicAdd(&cnt_s, 1);
            jidx[p] = i1; jdel[p] = sn1 - sm11;
        }
        #pragma unroll
        for (int m = 32; m >= 1; m >>= 1) cy &= __shfl_xor(cy, m, 64);
        if (lane == 0) part_c[wave] = cy;
        __syncthreads();   // flip list complete

        {
            const int c = cnt_s;
            #pragma unroll 8
            for (int t = 0; t < c; ++t) {
                const int j = jidx[t];
                const float d = jdel[t];
                const float2 wvv = *(const float2*)(w + (size_t)j * 512 + i0);
                h0 = fmaf(d, wvv.x, h0);
                h1 = fmaf(d, wvv.y, h1);
            }
        }
        float ep = sn0 * h0 + sn1 * h1;
        #pragma unroll
        for (int m = 32; m >= 1; m >>= 1) ep += __shfl_xor(ep, m, 64);
        if (lane == 0) part_e[wave] = ep;
        __syncthreads();

        if (tid == 0) {
            float e = -(part_e[0] + part_e[1] + part_e[2] + part_e[3]);
            int better = e < min_e_s;
            if (better) min_e_s = e;
            copyf_s = better;
            int fl = part_c[0] & part_c[1] & part_c[2] & part_c[3];
            int fixedp = (cnt_s == 0);
            int cyc = (k >= 2) && fl;
            if (fixedp || cyc) donef_s = 1;
            cnt_s = 0;
        }
        __syncthreads();

        if (copyf_s) { mins[i0] = sn0; mins[i1] = sn1; }
        sm20 = sm10; sm21 = sm11;
        sm10 = sn0;  sm11 = sn1;
        if (donef_s) break;
    }
    __syncthreads();

    const int j = tid & 127, half = tid >> 7;
    {
        const float4* rr = (const float4*)(rep + (size_t)j * 512 + half * 256);
        const float4* ms = (const float4*)(&mins[half * 256]);
        float p = 0.f;
        #pragma unroll 8
        for (int q = 0; q < 64; ++q) {
            float4 rv = rr[q], mv = ms[q];
            p += rv.x * mv.x + rv.y * mv.y + rv.z * mv.z + rv.w * mv.w;
        }
        red[tid] = p;
        __syncthreads();
        float v = 0.f;
        if (tid < 128) { v = fabsf(red[tid] + red[tid + 128]); red[tid] = v; }
        __syncthreads();
        for (int off = 64; off >= 1; off >>= 1) {
            if (tid < off) red[tid] = fmaxf(red[tid], red[tid + off]);
            __syncthreads();
        }
        float mx = red[0];
        __syncthreads();
        float ex = 0.f;
        if (tid < 128) { ex = expf(v - mx); red[tid] = ex; }
        __syncthreads();
        for (int off = 64; off >= 1; off >>= 1) {
            if (tid < off) red[tid] += red[tid + off];
            __syncthreads();
        }
        if (tid < 128) out[(size_t)row * 128 + tid] = ex / red[0];
    }
}

extern "C" void kernel_launch(void* const* d_in, const int* in_sizes, int n_in,
                              void* d_out, int out_size, void* d_ws, size_t ws_size,
                              hipStream_t stream) {
    const float* image = (const float*)d_in[0];
    const float* limg  = (const float*)d_in[1];
    const float* c1w   = (const float*)d_in[2];
    const float* c1b   = (const float*)d_in[3];
    const float* c2w   = (const float*)d_in[4];
    const float* c2b   = (const float*)d_in[5];
    const float* f1w   = (const float*)d_in[6];
    const float* f1b   = (const float*)d_in[7];
    const float* fnw   = (const float*)d_in[8];
    const float* fnb   = (const float*)d_in[9];
    float* out = (float*)d_out;
    float* ws  = (float*)d_ws;

    unsigned short* o1b  = (unsigned short*)ws;        // 1152*12800 us
    unsigned short* out2 = o1b + (size_t)NTOT * 12800; // 2*ASTR bf16
    float* lat  = (float*)(out2 + 2 * ASTR);           // 1024*512
    float* rep  = lat + (size_t)BATCH * 512;           // 128*512
    float* tT   = rep + (size_t)LABEL * 512;           // 512*128 (unused, layout)
    float* wmat = tT + (size_t)512 * 128;              // 512*512
    float* rho  = wmat + (size_t)512 * 512;            // 1 (+pad, layout)
    unsigned short* Bw2   = (unsigned short*)(rho + 16);   // 2*BSTR bf16
    unsigned short* Bfrag = Bw2 + 2 * BSTR;                // 102,400 bf16
    float* hmat = (float*)(Bfrag + 102400);            // 1024*512 f32
    unsigned short* lat2 = (unsigned short*)(hmat + A2STR);  // 2*A2STR bf16
    unsigned short* fnw2 = lat2 + 2 * A2STR;           // 2*W2STR bf16
    float* logits = (float*)(fnw2 + 2 * W2STR);        // 1024*128 f32
    float* part = (float*)ws;                          // alias o1b (dead after conv2)

    const int prep_total = 102400 + 512 * 3136 + 128 * 512;
    hipLaunchKernelGGL(prep, dim3((prep_total + 255) / 256), dim3(256), 0, stream,
                       c2w, f1w, fnw, Bfrag, Bw2, fnw2);
    hipLaunchKernelGGL(conv1_pool, dim3(NTOT), dim3(256), 0, stream, image, limg, c1w, c1b, o1b);
    hipLaunchKernelGGL(conv2_mfma, dim3(NTOT / 2), dim3(256), 0, stream, o1b, Bfrag, c2b, out2);
    hipLaunchKernelGGL(fc1_mfma, dim3(NTOT / 64, 512 / 64, 7), dim3(256), 0, stream,
                       out2, Bw2, part);
    hipLaunchKernelGGL(fc1_reduce, dim3(NTOT * 512 / 256), dim3(256), 0, stream,
                       part, f1b, lat, lat2, rep);
    hipLaunchKernelGGL(fcn_mfma, dim3(16, 2), dim3(256), 0, stream, lat2, fnw2, logits);
    hipLaunchKernelGGL(fcn_softmax2, dim3(BATCH), dim3(128), 0, stream, logits, fnb,
                       out + (size_t)BATCH * LABEL);
    hipLaunchKernelGGL(w_kernel, dim3(16, 16), dim3(256), 0, stream, rep, wmat);
    hipLaunchKernelGGL(hinit, dim3(BATCH / 64, 512 / 64), dim3(256), 0, stream, lat, wmat, hmat);
    hipLaunchKernelGGL(clustering, dim3(BATCH), dim3(256), 0, stream,
                       lat, hmat, wmat, rep, out);
}

// Round 8
// 371.367 us; speedup vs baseline: 1.0337x; 1.0239x over previous
//
#include <hip/hip_runtime.h>
#include <hip/hip_bf16.h>
#include <math.h>

#define BATCH 1024
#define LABEL 128
#define LATENT 512
#define NTOT 1152  // 1024 + 128

typedef short short8 __attribute__((ext_vector_type(8)));
typedef float f32x16 __attribute__((ext_vector_type(16)));

__device__ __forceinline__ unsigned short f2bf(float f) {
    __hip_bfloat16 h = __float2bfloat16(f);
    return *(unsigned short*)&h;
}
__device__ __forceinline__ float bf2f(unsigned short u) {
    __hip_bfloat16 h; *(unsigned short*)&h = u;
    return __bfloat162float(h);
}

#define BSTR ((size_t)512 * 3136)
#define ASTR ((size_t)NTOT * 3136)
#define A2STR ((size_t)BATCH * 512)
#define W2STR ((size_t)LABEL * 512)

// conv1 output layout (per image): 2 bf16 planes of 6400 ushorts.
// Plane = 196 compact pixels (14x14) x 32ch, granule = 64B, slot-swizzled:
// off = p*32 + (((oc>>3) ^ (p>>1)) & 3)*8 + (oc&7).  Granules 196..199 zeroed.
//
// NUMERICS RULE (r15): w_kernel/rho keep r14-exact op order (Hopfield sign
// cascades). COVERAGE RULE (r16): conv1 writes all 196 pixels (xh loop).
// r19 lesson: do not add kernels to the tail (launch+roundtrip > savings).
// r22/r23: conv2 v9.1 = 2 img/block dual-ocT waves, 83.3us PROVEN OPTIMUM.
// r24 (more occ) / r25 (manual pipeline) / r27 (conv1 fusion) — all WORSE.
// r26: rho in t_kernel; w_kernel LDS-tiled. 376.8us BEST.
// r28 lesson: inline rho per w-block -> VGPR 256 (unroll blowup) + 256x
// redundant rep reads = +3.5us. Idea right, placement wrong.
// r29: rho computed ONCE as an extra block (16,0) inside fcn_mfma (grid 32->34,
// 88% of GPU idle there -> free). w_kernel v5 = v4 minus inline rho (reads
// rho[0]); t_kernel stays deleted. All FP orders r14-exact -> bit-exact.

// ------- conv1 v3 (r17 proven) ------------------------------------------------
__global__ __launch_bounds__(256) void conv1_pool(const float* __restrict__ image,
                                                  const float* __restrict__ limg,
                                                  const float* __restrict__ wt,
                                                  const float* __restrict__ bias,
                                                  unsigned short* __restrict__ o1b) {
    const int n = blockIdx.x;
    const float* in = (n < BATCH) ? (image + (size_t)n * 784)
                                  : (limg + (size_t)(n - BATCH) * 784);
    __shared__ float pin[32][32];
    __shared__ float wts[32 * 25];
    const int tid = threadIdx.x;
    unsigned short* ob = o1b + (size_t)n * 12800;
    for (int i = tid; i < 256; i += 256) {
        int pl_ = i >> 7, r = i & 127;
        ob[pl_ * 6400 + 6272 + r] = 0;
    }
    for (int idx = tid; idx < 32 * 32; idx += 256) ((float*)pin)[idx] = 0.f;
    __syncthreads();
    for (int idx = tid; idx < 784; idx += 256) {
        int y = idx / 28, x = idx % 28;
        pin[y + 2][x + 2] = in[idx];
    }
    for (int idx = tid; idx < 800; idx += 256) wts[idx] = wt[idx];
    __syncthreads();
    const int oc = tid & 31;
    float wk[25];
    #pragma unroll
    for (int k = 0; k < 25; ++k) wk[k] = wts[oc * 25 + k];
    const float b = bias[oc];
    const int slot_lo = (oc & 7);
    const int gq = oc >> 3;
    for (int it = 0; it < 2; ++it) {
        const int py = (tid >> 5) + it * 8;
        if (py >= 14) continue;
        #pragma unroll
        for (int xh = 0; xh < 2; ++xh) {
            const int acol = xh ? 12 : 0;
            const int off = xh ? 2 : 0;
            float a0[14], a1[14];
            #pragma unroll
            for (int c = 0; c < 14; ++c) { a0[c] = b; a1[c] = b; }
            #pragma unroll
            for (int t = 0; t < 6; ++t) {
                float row[20];
                const float4* rp = (const float4*)&pin[2 * py + t][acol];
                #pragma unroll
                for (int v = 0; v < 5; ++v) {
                    float4 f = rp[v];
                    row[4 * v] = f.x; row[4 * v + 1] = f.y;
                    row[4 * v + 2] = f.z; row[4 * v + 3] = f.w;
                }
                if (t < 5) {
                    #pragma unroll
                    for (int kx = 0; kx < 5; ++kx) {
                        float w0 = wk[t * 5 + kx];
                        #pragma unroll
                        for (int c = 0; c < 14; ++c)
                            a0[c] = fmaf(row[c + kx + off], w0, a0[c]);
                    }
                }
                if (t >= 1) {
                    #pragma unroll
                    for (int kx = 0; kx < 5; ++kx) {
                        float w1 = wk[(t - 1) * 5 + kx];
                        #pragma unroll
                        for (int c = 0; c < 14; ++c)
                            a1[c] = fmaf(row[c + kx + off], w1, a1[c]);
                    }
                }
            }
            #pragma unroll
            for (int px = 0; px < 7; ++px) {
                float v = fmaxf(fmaxf(a0[2 * px], a0[2 * px + 1]),
                                fmaxf(a1[2 * px], a1[2 * px + 1]));
                v = fmaxf(v, 0.f);
                unsigned short b1 = f2bf(v);
                unsigned short b2 = f2bf(v - bf2f(b1));
                int p = py * 14 + 7 * xh + px;
                int offo = p * 32 + (((gq ^ (p >> 1)) & 3) << 3) + slot_lo;
                ob[offo] = b1; ob[6400 + offo] = b2;
            }
        }
    }
}

// ------- merged prep (r17 proven) ---------------------------------------------
__global__ __launch_bounds__(256) void prep(const float* __restrict__ c2w,
                                            const float* __restrict__ f1w,
                                            const float* __restrict__ fnw,
                                            unsigned short* __restrict__ Bf,
                                            unsigned short* __restrict__ Bw2,
                                            unsigned short* __restrict__ Bn2) {
    int idx = blockIdx.x * 256 + threadIdx.x;
    if (idx < 102400) {
        int j = idx & 7, lane = (idx >> 3) & 63, ocT = (idx >> 9) & 1, s = idx >> 10;
        int q = lane >> 5, nn = lane & 31;
        int k = 16 * s + 8 * q + j;
        int tap = k >> 5, ic = k & 31;
        int oc = 32 * ocT + nn;
        float v = c2w[oc * 800 + ic * 25 + tap];
        unsigned short b1 = f2bf(v);
        unsigned short b2 = f2bf(v - bf2f(b1));
        size_t base = ((size_t)(s * 2 + ocT) * 2) * 512 + lane * 8 + j;
        Bf[base] = b1; Bf[base + 512] = b2;
        return;
    }
    int i2 = idx - 102400;
    if (i2 < 512 * 3136) {
        float v = f1w[i2];
        unsigned short b1 = f2bf(v);
        unsigned short b2 = f2bf(v - bf2f(b1));
        Bw2[i2] = b1; Bw2[BSTR + i2] = b2;
        return;
    }
    int i3 = i2 - 512 * 3136;
    if (i3 >= 128 * 512) return;
    float v = fnw[i3];
    unsigned short b1 = f2bf(v);
    unsigned short b2 = f2bf(v - bf2f(b1));
    Bn2[i3] = b1; Bn2[W2STR + i3] = b2;
}

// ------- conv2 via MFMA v9.1 (r23 PROVEN, verbatim): 2 img/block --------------
template<int NT>
__device__ __forceinline__ void conv2_kloop2(const unsigned short* __restrict__ pl,
                                             const unsigned short* __restrict__ Bf,
                                             const int lane, const int q,
                                             const int* __restrict__ ym,
                                             const int* __restrict__ xm,
                                             const int* __restrict__ mm,
                                             const float bs0, const float bs1,
                                             f32x16* __restrict__ acc) {
    #pragma unroll
    for (int im = 0; im < 2; ++im)
    #pragma unroll
    for (int oc = 0; oc < 2; ++oc) {
        const float bs = oc ? bs1 : bs0;
        #pragma unroll
        for (int tt = 0; tt < NT; ++tt)
        #pragma unroll
        for (int r = 0; r < 16; ++r) acc[(im * 2 + oc) * NT + tt][r] = bs;
    }
    for (int s = 0; s < 50; ++s) {
        const unsigned short* bp = Bf + (size_t)s * 2048 + lane * 8;
        short8 b1[2], b2[2];
        b1[0] = *(const short8*)(bp);
        b2[0] = *(const short8*)(bp + 512);
        b1[1] = *(const short8*)(bp + 1024);
        b2[1] = *(const short8*)(bp + 1536);
        const int kb = 16 * s + 8 * q;
        const int tap = kb >> 5, g = (kb & 31) >> 3;
        const int ky = (tap * 13) >> 6;       // exact /5 for tap<25
        const int kx = tap - ky * 5;
        const int iyk = ky - 2, ixk = kx - 2;
        const int pq2 = iyk * 14 + ixk;
        int addr[NT];
        #pragma unroll
        for (int tt = 0; tt < NT; ++tt) {
            int iy = ym[tt] + iyk, ix = xm[tt] + ixk;
            int valid = ((unsigned)iy < 14u) & ((unsigned)ix < 14u);
            int cpt = valid ? (mm[tt] + pq2) : 196;
            addr[tt] = cpt * 32 + (((g ^ (cpt >> 1)) & 3) << 3);
        }
        short8 a1[2][NT], a2[2][NT];
        #pragma unroll
        for (int im = 0; im < 2; ++im) {
            const unsigned short* pli = pl + im * 12800;
            #pragma unroll
            for (int tt = 0; tt < NT; ++tt) {
                a1[im][tt] = *(const short8*)(pli + addr[tt]);
                a2[im][tt] = *(const short8*)(pli + 6400 + addr[tt]);
            }
        }
        #pragma unroll
        for (int im = 0; im < 2; ++im)
        #pragma unroll
        for (int oc = 0; oc < 2; ++oc)
        #pragma unroll
        for (int tt = 0; tt < NT; ++tt) {
            f32x16 a = acc[(im * 2 + oc) * NT + tt];
            a = __builtin_amdgcn_mfma_f32_32x32x16_bf16(a1[im][tt], b1[oc], a, 0, 0, 0);
            a = __builtin_amdgcn_mfma_f32_32x32x16_bf16(a1[im][tt], b2[oc], a, 0, 0, 0);
            a = __builtin_amdgcn_mfma_f32_32x32x16_bf16(a2[im][tt], b1[oc], a, 0, 0, 0);
            acc[(im * 2 + oc) * NT + tt] = a;
        }
    }
}

template<int NT>
__device__ __forceinline__ void conv2_epi(const f32x16* __restrict__ acc,
                                          float* __restrict__ hx,
                                          const int wv, const int m_, const int q) {
    #pragma unroll
    for (int im = 0; im < 2; ++im) {
        float* hxi = hx + im * 6400;
        #pragma unroll
        for (int oc = 0; oc < 2; ++oc) {
            const int occ = 32 * oc + m_;
            #pragma unroll
            for (int tt = 0; tt < NT; ++tt)
            #pragma unroll
            for (int e = 0; e < 8; ++e) {
                const int reg = 2 * e;
                const int r = (reg & 3) + 8 * (reg >> 2) + 4 * q;
                const int m = 32 * (2 * wv + tt) + r;
                if (m < 196) {
                    float xm2 = fmaxf(acc[(im * 2 + oc) * NT + tt][reg],
                                      acc[(im * 2 + oc) * NT + tt][reg + 1]);
                    int y = (m * 2341) >> 15;
                    int px = (m - 14 * y) >> 1;
                    hxi[(y * 7 + px) * 65 + occ] = xm2;
                }
            }
        }
    }
}

__global__ __launch_bounds__(256, 2) void conv2_mfma(const unsigned short* __restrict__ o1b,
                                                     const unsigned short* __restrict__ Bf,
                                                     const float* __restrict__ bias,
                                                     unsigned short* __restrict__ out2) {
    const int n2 = blockIdx.x;            // image pair (2*n2, 2*n2+1)
    __shared__ __align__(16) unsigned short pl[2 * 12800];
    const int tid = threadIdx.x;
    const int lane = tid & 63, wv = tid >> 6;   // wv = m-tile pair index

    {
        const float4* src = (const float4*)(o1b + (size_t)n2 * 25600);
        float4* dst = (float4*)pl;
        for (int i = tid; i < 3200; i += 256) dst[i] = src[i];
    }
    __syncthreads();

    const int m_ = lane & 31, q = lane >> 5;
    int ym[2], xm[2], mm[2];
    #pragma unroll
    for (int tt = 0; tt < 2; ++tt) {
        int t = 2 * wv + tt;
        if (t > 6) t = 6;               // wv=3,tt=1 dummy (kloop<1> never uses it)
        int m = 32 * t + m_;
        mm[tt] = m;
        ym[tt] = m / 14;
        xm[tt] = m - 14 * ym[tt];
    }
    const float bs0 = bias[m_];
    const float bs1 = bias[32 + m_];
    f32x16 acc[8];

    if (wv < 3) conv2_kloop2<2>(pl, Bf, lane, q, ym, xm, mm, bs0, bs1, acc);
    else        conv2_kloop2<1>(pl, Bf, lane, q, ym, xm, mm, bs0, bs1, acc);
    __syncthreads();

    float* hx = (float*)pl;   // 12800 floats total; per-image stride 6400
    if (wv < 3) conv2_epi<2>(acc, hx, wv, m_, q);
    else        conv2_epi<1>(acc, hx, wv, m_, q);
    __syncthreads();

    for (int ii = tid; ii < 6272; ii += 256) {
        const int im = (ii >= 3136) ? 1 : 0;
        const int idx = ii - (im ? 3136 : 0);
        const float* hxi = hx + im * 6400;
        int oc2 = (idx * 2675) >> 17;
        int p = idx - 49 * oc2;
        int py = (p * 9363) >> 16;
        int px = p - 7 * py;
        float v = fmaxf(hxi[(2 * py * 7 + px) * 65 + oc2],
                        hxi[((2 * py + 1) * 7 + px) * 65 + oc2]);
        v = fmaxf(v, 0.f);
        unsigned short b1 = f2bf(v);
        unsigned short b2 = f2bf(v - bf2f(b1));
        size_t o = (size_t)n2 * 6272 + ii;
        out2[o] = b1; out2[ASTR + o] = b2;
    }
}

// ------- fc1 via MFMA (r14 proven) --------------------------------------------
__global__ __launch_bounds__(256) void fc1_mfma(const unsigned short* __restrict__ A2,
                                                const unsigned short* __restrict__ B2,
                                                float* __restrict__ part) {
    __shared__ unsigned short As[2][2048];
    __shared__ unsigned short Bs[2][2048];
    const int tid = threadIdx.x;
    const int n0 = blockIdx.x * 64, m0 = blockIdx.y * 64;
    const int koff = blockIdx.z * 448;
    const int lr = tid >> 2, g = tid & 3;
    const int slot = (((g ^ (lr >> 1)) & 3) << 3);
    const int lane = tid & 63, wv = tid >> 6;
    const int nq = wv & 1, mq = wv >> 1;
    const int q = lane >> 5, l31 = lane & 31;
    const int rA = 32 * nq + l31, rB = 32 * mq + l31;
    f32x16 acc;
    #pragma unroll
    for (int r = 0; r < 16; ++r) acc[r] = 0.f;

    for (int bk = 0; bk < 448; bk += 32) {
        const size_t ka = (size_t)(koff + bk + (g << 3));
        short8 av[2], bv[2];
        #pragma unroll
        for (int p = 0; p < 2; ++p) {
            av[p] = *(const short8*)(A2 + p * ASTR + (size_t)(n0 + lr) * 3136 + ka);
            bv[p] = *(const short8*)(B2 + p * BSTR + (size_t)(m0 + lr) * 3136 + ka);
        }
        __syncthreads();
        #pragma unroll
        for (int p = 0; p < 2; ++p) {
            *(short8*)&As[p][(lr << 5) + slot] = av[p];
            *(short8*)&Bs[p][(lr << 5) + slot] = bv[p];
        }
        __syncthreads();
        #pragma unroll
        for (int s2 = 0; s2 < 32; s2 += 16) {
            const int gg = (s2 + (q << 3)) >> 3;
            const int sa = (((gg ^ (rA >> 1)) & 3) << 3);
            const int sb = (((gg ^ (rB >> 1)) & 3) << 3);
            short8 a1 = *(const short8*)&As[0][(rA << 5) + sa];
            short8 a2 = *(const short8*)&As[1][(rA << 5) + sa];
            short8 b1 = *(const short8*)&Bs[0][(rB << 5) + sb];
            short8 b2 = *(const short8*)&Bs[1][(rB << 5) + sb];
            acc = __builtin_amdgcn_mfma_f32_32x32x16_bf16(a1, b1, acc, 0, 0, 0);
            acc = __builtin_amdgcn_mfma_f32_32x32x16_bf16(a1, b2, acc, 0, 0, 0);
            acc = __builtin_amdgcn_mfma_f32_32x32x16_bf16(a2, b1, acc, 0, 0, 0);
        }
    }
    float* pb = part + (size_t)blockIdx.z * NTOT * 512;
    #pragma unroll
    for (int reg = 0; reg < 16; ++reg) {
        int nn = n0 + 32 * nq + (reg & 3) + 8 * (reg >> 2) + 4 * q;
        int mmo = m0 + 32 * mq + l31;
        pb[(size_t)nn * 512 + mmo] = acc[reg];
    }
}

__global__ __launch_bounds__(256) void fc1_reduce(const float* __restrict__ part,
                                                  const float* __restrict__ bias,
                                                  float* __restrict__ lat,
                                                  unsigned short* __restrict__ lat2,
                                                  float* __restrict__ rep) {
    int idx = blockIdx.x * 256 + threadIdx.x;
    int m = idx & 511;
    float v = bias[m];
    #pragma unroll
    for (int kz = 0; kz < 7; ++kz) v += part[(size_t)kz * NTOT * 512 + idx];
    if (idx < BATCH * 512) {
        lat[idx] = v;
        unsigned short b1 = f2bf(v);
        lat2[idx] = b1;
        lat2[A2STR + idx] = f2bf(v - bf2f(b1));
    } else {
        rep[idx - BATCH * 512] = tanhf(v);
    }
}

// ------- fcn logits via MFMA (r17) + rho side-block (r29) ---------------------
__global__ __launch_bounds__(256) void fcn_mfma(const unsigned short* __restrict__ A2,
                                                const unsigned short* __restrict__ B2,
                                                const float* __restrict__ rep,
                                                float* __restrict__ rho,
                                                float* __restrict__ logits) {
    __shared__ unsigned short As[2][2048];
    __shared__ unsigned short Bs[2][2048];
    __shared__ float red[256];
    const int tid = threadIdx.x;
    if (blockIdx.x == 16) {
        // rho side-block: EXACT replica of r14 rho_kernel (256-thread strided
        // sum + 128..1 tree + divide) => bit-identical rho[0]. Runs in the
        // shadow of the 32 GEMM blocks (GPU is 88% idle in this launch).
        if (blockIdx.y == 0) {
            float s = 0.f;
            #pragma unroll 1
            for (int i = tid; i < LABEL * LATENT; i += 256) s += rep[i];
            red[tid] = s;
            __syncthreads();
            for (int off = 128; off >= 1; off >>= 1) {
                if (tid < off) red[tid] += red[tid + off];
                __syncthreads();
            }
            if (tid == 0) rho[0] = red[0] / (float)(LABEL * LATENT);
        }
        return;
    }
    const int n0 = blockIdx.x * 64, m0 = blockIdx.y * 64;
    const int lr = tid >> 2, g = tid & 3;
    const int slot = (((g ^ (lr >> 1)) & 3) << 3);
    const int lane = tid & 63, wv = tid >> 6;
    const int nq = wv & 1, mq = wv >> 1;
    const int q = lane >> 5, l31 = lane & 31;
    const int rA = 32 * nq + l31, rB = 32 * mq + l31;
    f32x16 acc;
    #pragma unroll
    for (int r = 0; r < 16; ++r) acc[r] = 0.f;

    for (int bk = 0; bk < 512; bk += 32) {
        const size_t ka = (size_t)(bk + (g << 3));
        short8 av[2], bv[2];
        #pragma unroll
        for (int p = 0; p < 2; ++p) {
            av[p] = *(const short8*)(A2 + p * A2STR + (size_t)(n0 + lr) * 512 + ka);
            bv[p] = *(const short8*)(B2 + p * W2STR + (size_t)(m0 + lr) * 512 + ka);
        }
        __syncthreads();
        #pragma unroll
        for (int p = 0; p < 2; ++p) {
            *(short8*)&As[p][(lr << 5) + slot] = av[p];
            *(short8*)&Bs[p][(lr << 5) + slot] = bv[p];
        }
        __syncthreads();
        #pragma unroll
        for (int s2 = 0; s2 < 32; s2 += 16) {
            const int gg = (s2 + (q << 3)) >> 3;
            const int sa = (((gg ^ (rA >> 1)) & 3) << 3);
            const int sb = (((gg ^ (rB >> 1)) & 3) << 3);
            short8 a1 = *(const short8*)&As[0][(rA << 5) + sa];
            short8 a2 = *(const short8*)&As[1][(rA << 5) + sa];
            short8 b1 = *(const short8*)&Bs[0][(rB << 5) + sb];
            short8 b2 = *(const short8*)&Bs[1][(rB << 5) + sb];
            acc = __builtin_amdgcn_mfma_f32_32x32x16_bf16(a1, b1, acc, 0, 0, 0);
            acc = __builtin_amdgcn_mfma_f32_32x32x16_bf16(a1, b2, acc, 0, 0, 0);
            acc = __builtin_amdgcn_mfma_f32_32x32x16_bf16(a2, b1, acc, 0, 0, 0);
        }
    }
    #pragma unroll
    for (int reg = 0; reg < 16; ++reg) {
        int nn = n0 + 32 * nq + (reg & 3) + 8 * (reg >> 2) + 4 * q;
        int mmo = m0 + 32 * mq + l31;
        logits[(size_t)nn * 128 + mmo] = acc[reg];
    }
}

__global__ __launch_bounds__(128) void fcn_softmax2(const float* __restrict__ logits,
                                                    const float* __restrict__ fb,
                                                    float* __restrict__ out) {
    const int b = blockIdx.x;
    const int j = threadIdx.x;
    __shared__ float red[128];
    float acc = logits[(size_t)b * 128 + j] + fb[j];
    red[j] = acc;
    __syncthreads();
    for (int off = 64; off >= 1; off >>= 1) {
        if (j < off) red[j] = fmaxf(red[j], red[j + off]);
        __syncthreads();
    }
    float mx = red[0];
    __syncthreads();
    float ex = expf(acc - mx);
    red[j] = ex;
    __syncthreads();
    for (int off = 64; off >= 1; off >>= 1) {
        if (j < off) red[j] += red[j + off];
        __syncthreads();
    }
    out[(size_t)b * 128 + j] = ex / red[0];
}

// ------- w_kernel v5 (r29): direct-from-rep, rho from global, bit-exact -------
// As_f[r][k] = rep[k][i0+r] - r0 == tT[i0+r][k] (identical bits to r26 path).
// Compute loop identical to v3 -> identical FP results.
__global__ __launch_bounds__(256) void w_kernel(const float* __restrict__ rep,
                                                const float* __restrict__ rho,
                                                float* __restrict__ w) {
    __shared__ float4 As[32][33];
    __shared__ float4 Bs[32][33];
    const int tid = threadIdx.x;
    const float r0 = rho[0];
    const int i0 = blockIdx.x * 32, j0 = blockIdx.y * 32;
    float* Asf = (float*)As;   // row stride 132 floats
    float* Bsf = (float*)Bs;
    const int tx = tid & 31, ty = tid >> 5;   // 32 cols x 8 rows per pass
    #pragma unroll 4
    for (int pass = 0; pass < 16; ++pass) {
        const int k = pass * 8 + ty;
        Asf[tx * 132 + k] = rep[(size_t)k * 512 + i0 + tx] - r0;
        Bsf[tx * 132 + k] = rep[(size_t)k * 512 + j0 + tx] - r0;
    }
    __syncthreads();
    const int ty2 = tid >> 4, tx2 = tid & 15;   // 16x16 threads, 2x2 outputs each
    float acc[2][2] = {};
    for (int q = 0; q < 32; ++q) {
        float4 a4[2], b4[2];
        #pragma unroll
        for (int d = 0; d < 2; ++d) { a4[d] = As[ty2 * 2 + d][q]; b4[d] = Bs[tx2 * 2 + d][q]; }
        #pragma unroll
        for (int di = 0; di < 2; ++di)
        #pragma unroll
        for (int dj = 0; dj < 2; ++dj)
            acc[di][dj] += a4[di].x * b4[dj].x + a4[di].y * b4[dj].y +
                           a4[di].z * b4[dj].z + a4[di].w * b4[dj].w;
    }
    #pragma unroll
    for (int di = 0; di < 2; ++di)
    #pragma unroll
    for (int dj = 0; dj < 2; ++dj) {
        int i = i0 + ty2 * 2 + di, j = j0 + tx2 * 2 + dj;
        w[(size_t)i * 512 + j] = (i == j) ? 0.f : acc[di][dj] * (1.f / 128.f);
    }
}

// ------- hinit (r14 proven) ---------------------------------------------------
__global__ __launch_bounds__(256) void hinit(const float* __restrict__ lat,
                                             const float* __restrict__ w,
                                             float* __restrict__ hmat) {
    __shared__ float As[16][68];
    __shared__ float Bs[16][68];
    const int tid = threadIdx.x;
    const int n0 = blockIdx.x * 64, m0 = blockIdx.y * 64;
    const int lr = tid >> 2;
    const int lk = (tid & 3) * 4;
    const int ty = tid >> 4, tx = tid & 15;
    float c[4][4] = {};
    for (int k0 = 0; k0 < 512; k0 += 16) {
        float4 a4 = *(const float4*)(lat + (size_t)(n0 + lr) * 512 + k0 + lk);
        float4 b4 = *(const float4*)(w + (size_t)(m0 + lr) * 512 + k0 + lk);
        a4.x = tanhf(a4.x); a4.y = tanhf(a4.y); a4.z = tanhf(a4.z); a4.w = tanhf(a4.w);
        __syncthreads();
        As[lk + 0][lr] = a4.x; As[lk + 1][lr] = a4.y; As[lk + 2][lr] = a4.z; As[lk + 3][lr] = a4.w;
        Bs[lk + 0][lr] = b4.x; Bs[lk + 1][lr] = b4.y; Bs[lk + 2][lr] = b4.z; Bs[lk + 3][lr] = b4.w;
        __syncthreads();
        #pragma unroll
        for (int kk = 0; kk < 16; ++kk) {
            float av[4], bv[4];
            #pragma unroll
            for (int i = 0; i < 4; ++i) av[i] = As[kk][ty * 4 + i];
            #pragma unroll
            for (int j = 0; j < 4; ++j) bv[j] = Bs[kk][tx * 4 + j];
            #pragma unroll
            for (int i = 0; i < 4; ++i)
            #pragma unroll
            for (int j = 0; j < 4; ++j) c[i][j] += av[i] * bv[j];
        }
    }
    #pragma unroll
    for (int i = 0; i < 4; ++i)
    #pragma unroll
    for (int j = 0; j < 4; ++j)
        hmat[(size_t)(n0 + ty * 4 + i) * 512 + m0 + tx * 4 + j] = c[i][j];
}

// ------- clustering v3 (r18 proven): CB=1, incremental Hopfield ---------------
__device__ __forceinline__ float sgnf(float x) {
    return (x > 0.f) ? 1.f : ((x < 0.f) ? -1.f : 0.f);
}

__global__ __launch_bounds__(256) void clustering(const float* __restrict__ lat,
                                                  const float* __restrict__ hmat,
                                                  const float* __restrict__ w,
                                                  const float* __restrict__ rep,
                                                  float* __restrict__ out) {
    const int tid = threadIdx.x;
    const int row = blockIdx.x;
    __shared__ float mins[512];
    __shared__ float red[256];
    __shared__ float part_e[4];
    __shared__ int part_c[4];
    __shared__ float min_e_s;
    __shared__ int copyf_s;
    __shared__ int donef_s;
    __shared__ int cnt_s;
    __shared__ int jidx[512];
    __shared__ float jdel[512];
    const int i0 = 2 * tid, i1 = 2 * tid + 1;
    const int wave = tid >> 6, lane = tid & 63;

    float sm10, sm11, sm20, sm21, h0, h1;
    {
        sm10 = tanhf(lat[(size_t)row * 512 + i0]);
        sm11 = tanhf(lat[(size_t)row * 512 + i1]);
        sm20 = sm10; sm21 = sm11;
        h0 = hmat[(size_t)row * 512 + i0];
        h1 = hmat[(size_t)row * 512 + i1];
    }
    if (tid == 0) { min_e_s = INFINITY; donef_s = 0; cnt_s = 0; }
    __syncthreads();

    for (int k = 1; k <= 512; ++k) {
        float sn0 = fabsf(sm10) * sgnf(h0);
        float sn1 = fabsf(sm11) * sgnf(h1);
        int cy = (sn0 == sm20 && sn1 == sm21) ? 1 : 0;
        if (sn0 != sm10) {
            int p = atomicAdd(&cnt_s, 1);
            jidx[p] = i0; jdel[p] = sn0 - sm10;
        }
        if (sn1 != sm11) {
            int p = atomicAdd(&cnt_s, 1);
            jidx[p] = i1; jdel[p] = sn1 - sm11;
        }
        #pragma unroll
        for (int m = 32; m >= 1; m >>= 1) cy &= __shfl_xor(cy, m, 64);
        if (lane == 0) part_c[wave] = cy;
        __syncthreads();   // flip list complete

        {
            const int c = cnt_s;
            #pragma unroll 8
            for (int t = 0; t < c; ++t) {
                const int j = jidx[t];
                const float d = jdel[t];
                const float2 wvv = *(const float2*)(w + (size_t)j * 512 + i0);
                h0 = fmaf(d, wvv.x, h0);
                h1 = fmaf(d, wvv.y, h1);
            }
        }
        float ep = sn0 * h0 + sn1 * h1;
        #pragma unroll
        for (int m = 32; m >= 1; m >>= 1) ep += __shfl_xor(ep, m, 64);
        if (lane == 0) part_e[wave] = ep;
        __syncthreads();

        if (tid == 0) {
            float e = -(part_e[0] + part_e[1] + part_e[2] + part_e[3]);
            int better = e < min_e_s;
            if (better) min_e_s = e;
            copyf_s = better;
            int fl = part_c[0] & part_c[1] & part_c[2] & part_c[3];
            int fixedp = (cnt_s == 0);
            int cyc = (k >= 2) && fl;
            if (fixedp || cyc) donef_s = 1;
            cnt_s = 0;
        }
        __syncthreads();

        if (copyf_s) { mins[i0] = sn0; mins[i1] = sn1; }
        sm20 = sm10; sm21 = sm11;
        sm10 = sn0;  sm11 = sn1;
        if (donef_s) break;
    }
    __syncthreads();

    const int j = tid & 127, half = tid >> 7;
    {
        const float4* rr = (const float4*)(rep + (size_t)j * 512 + half * 256);
        const float4* ms = (const float4*)(&mins[half * 256]);
        float p = 0.f;
        #pragma unroll 8
        for (int q = 0; q < 64; ++q) {
            float4 rv = rr[q], mv = ms[q];
            p += rv.x * mv.x + rv.y * mv.y + rv.z * mv.z + rv.w * mv.w;
        }
        red[tid] = p;
        __syncthreads();
        float v = 0.f;
        if (tid < 128) { v = fabsf(red[tid] + red[tid + 128]); red[tid] = v; }
        __syncthreads();
        for (int off = 64; off >= 1; off >>= 1) {
            if (tid < off) red[tid] = fmaxf(red[tid], red[tid + off]);
            __syncthreads();
        }
        float mx = red[0];
        __syncthreads();
        float ex = 0.f;
        if (tid < 128) { ex = expf(v - mx); red[tid] = ex; }
        __syncthreads();
        for (int off = 64; off >= 1; off >>= 1) {
            if (tid < off) red[tid] += red[tid + off];
            __syncthreads();
        }
        if (tid < 128) out[(size_t)row * 128 + tid] = ex / red[0];
    }
}

extern "C" void kernel_launch(void* const* d_in, const int* in_sizes, int n_in,
                              void* d_out, int out_size, void* d_ws, size_t ws_size,
                              hipStream_t stream) {
    const float* image = (const float*)d_in[0];
    const float* limg  = (const float*)d_in[1];
    const float* c1w   = (const float*)d_in[2];
    const float* c1b   = (const float*)d_in[3];
    const float* c2w   = (const float*)d_in[4];
    const float* c2b   = (const float*)d_in[5];
    const float* f1w   = (const float*)d_in[6];
    const float* f1b   = (const float*)d_in[7];
    const float* fnw   = (const float*)d_in[8];
    const float* fnb   = (const float*)d_in[9];
    float* out = (float*)d_out;
    float* ws  = (float*)d_ws;

    unsigned short* o1b  = (unsigned short*)ws;        // 1152*12800 us
    unsigned short* out2 = o1b + (size_t)NTOT * 12800; // 2*ASTR bf16
    float* lat  = (float*)(out2 + 2 * ASTR);           // 1024*512
    float* rep  = lat + (size_t)BATCH * 512;           // 128*512
    float* tT   = rep + (size_t)LABEL * 512;           // 512*128 (unused, layout)
    float* wmat = tT + (size_t)512 * 128;              // 512*512
    float* rho  = wmat + (size_t)512 * 512;            // 1 (+pad)
    unsigned short* Bw2   = (unsigned short*)(rho + 16);   // 2*BSTR bf16
    unsigned short* Bfrag = Bw2 + 2 * BSTR;                // 102,400 bf16
    float* hmat = (float*)(Bfrag + 102400);            // 1024*512 f32
    unsigned short* lat2 = (unsigned short*)(hmat + A2STR);  // 2*A2STR bf16
    unsigned short* fnw2 = lat2 + 2 * A2STR;           // 2*W2STR bf16
    float* logits = (float*)(fnw2 + 2 * W2STR);        // 1024*128 f32
    float* part = (float*)ws;                          // alias o1b (dead after conv2)

    const int prep_total = 102400 + 512 * 3136 + 128 * 512;
    hipLaunchKernelGGL(prep, dim3((prep_total + 255) / 256), dim3(256), 0, stream,
                       c2w, f1w, fnw, Bfrag, Bw2, fnw2);
    hipLaunchKernelGGL(conv1_pool, dim3(NTOT), dim3(256), 0, stream, image, limg, c1w, c1b, o1b);
    hipLaunchKernelGGL(conv2_mfma, dim3(NTOT / 2), dim3(256), 0, stream, o1b, Bfrag, c2b, out2);
    hipLaunchKernelGGL(fc1_mfma, dim3(NTOT / 64, 512 / 64, 7), dim3(256), 0, stream,
                       out2, Bw2, part);
    hipLaunchKernelGGL(fc1_reduce, dim3(NTOT * 512 / 256), dim3(256), 0, stream,
                       part, f1b, lat, lat2, rep);
    hipLaunchKernelGGL(fcn_mfma, dim3(17, 2), dim3(256), 0, stream,
                       lat2, fnw2, rep, rho, logits);
    hipLaunchKernelGGL(fcn_softmax2, dim3(BATCH), dim3(128), 0, stream, logits, fnb,
                       out + (size_t)BATCH * LABEL);
    hipLaunchKernelGGL(w_kernel, dim3(16, 16), dim3(256), 0, stream, rep, rho, wmat);
    hipLaunchKernelGGL(hinit, dim3(BATCH / 64, 512 / 64), dim3(256), 0, stream, lat, wmat, hmat);
    hipLaunchKernelGGL(clustering, dim3(BATCH), dim3(256), 0, stream,
                       lat, hmat, wmat, rep, out);
}